// Round 1
// baseline (3385.205 us; speedup 1.0000x reference)
//
#include <hip/hip_runtime.h>
#include <math.h>

// Problem constants
#define BB 2
#define NN 2048
#define DD 1024
#define HH 16
#define DH 64
#define ROWS (BB * NN)          // 4096
#define QKVH_COLS 5120          // q|k|v|hk|hv
#define SCALE 0.125f            // Dh^-0.5

__device__ __forceinline__ int sw16(int c4, int r) { return (c4 ^ (r >> 2)) & 15; }

// ---------------------------------------------------------------------------
// Generic fp32 GEMM: C[M x Ncols] = A[M x K] @ Bcat + bias
// Bcat column c: c < split -> B0[:, c] (ld ldb0), else B1[:, c-split] (ld ldb1)
// 128x128 tile, BK=16, 256 threads, 8x8 per thread, swizzled LDS.
// ---------------------------------------------------------------------------
__global__ __launch_bounds__(256)
void gemm128(const float* __restrict__ A, int lda,
             const float* __restrict__ B0, int ldb0,
             const float* __restrict__ B1, int ldb1, int split,
             const float* __restrict__ bias,
             float* __restrict__ C, int ldc, int K)
{
    __shared__ float As[16 * 128];   // AsT[kk][128], float4 slots swizzled
    __shared__ float Bs[16 * 128];   // Bs[kk][128],  float4 slots swizzled

    const int tid = threadIdx.x;
    const int ty = tid >> 4, tx = tid & 15;
    const int rb = blockIdx.y * 128, cb = blockIdx.x * 128;

    float acc[8][8];
#pragma unroll
    for (int i = 0; i < 8; ++i)
#pragma unroll
        for (int j = 0; j < 8; ++j) acc[i][j] = 0.f;

    for (int k0 = 0; k0 < K; k0 += 16) {
        __syncthreads();
        // ---- load A tile (128 rows x 16 k), store transposed+swizzled
#pragma unroll
        for (int t = 0; t < 2; ++t) {
            int idx = tid + 256 * t;
            int ar = idx >> 2, ak4 = idx & 3;
            float4 av = *(const float4*)&A[(size_t)(rb + ar) * lda + k0 + 4 * ak4];
            int s = ar >> 2, e = ar & 3;
            int kk = 4 * ak4;
            As[(kk + 0) * 128 + (((s ^ ((kk + 0) << 1)) & 31) << 2) + e] = av.x;
            As[(kk + 1) * 128 + (((s ^ ((kk + 1) << 1)) & 31) << 2) + e] = av.y;
            As[(kk + 2) * 128 + (((s ^ ((kk + 2) << 1)) & 31) << 2) + e] = av.z;
            As[(kk + 3) * 128 + (((s ^ ((kk + 3) << 1)) & 31) << 2) + e] = av.w;
        }
        // ---- load B tile (16 k x 128 cols)
#pragma unroll
        for (int t = 0; t < 2; ++t) {
            int idx = tid + 256 * t;
            int bk = idx >> 5, bc4 = idx & 31;
            int col = cb + 4 * bc4;
            const float* bp = (col < split)
                                  ? (B0 + (size_t)(k0 + bk) * ldb0 + col)
                                  : (B1 + (size_t)(k0 + bk) * ldb1 + (col - split));
            ((float4*)Bs)[bk * 32 + ((bc4 ^ (bk << 1)) & 31)] = *(const float4*)bp;
        }
        __syncthreads();
#pragma unroll
        for (int kk = 0; kk < 16; ++kk) {
            float4 a0 = ((float4*)As)[kk * 32 + (((2 * ty + 0) ^ (kk << 1)) & 31)];
            float4 a1 = ((float4*)As)[kk * 32 + (((2 * ty + 1) ^ (kk << 1)) & 31)];
            float4 b0 = ((float4*)Bs)[kk * 32 + (((2 * tx + 0) ^ (kk << 1)) & 31)];
            float4 b1 = ((float4*)Bs)[kk * 32 + (((2 * tx + 1) ^ (kk << 1)) & 31)];
            float a[8] = {a0.x, a0.y, a0.z, a0.w, a1.x, a1.y, a1.z, a1.w};
            float b[8] = {b0.x, b0.y, b0.z, b0.w, b1.x, b1.y, b1.z, b1.w};
#pragma unroll
            for (int i = 0; i < 8; ++i)
#pragma unroll
                for (int j = 0; j < 8; ++j)
                    acc[i][j] = fmaf(a[i], b[j], acc[i][j]);
        }
    }
    // ---- store
#pragma unroll
    for (int i = 0; i < 8; ++i) {
        int row = rb + 8 * ty + i;
#pragma unroll
        for (int p = 0; p < 2; ++p) {
            int col = cb + 8 * tx + 4 * p;
            float4 o = make_float4(acc[i][4 * p + 0], acc[i][4 * p + 1],
                                   acc[i][4 * p + 2], acc[i][4 * p + 3]);
            if (bias) {
                o.x += bias[col + 0]; o.y += bias[col + 1];
                o.z += bias[col + 2]; o.w += bias[col + 3];
            }
            *(float4*)&C[(size_t)row * ldc + col] = o;
        }
    }
}

// ---------------------------------------------------------------------------
// In-place interleaved RoPE on q (cols 0..1023) and k (cols 1024..2047)
// ---------------------------------------------------------------------------
__global__ __launch_bounds__(256)
void rope_kernel(float* __restrict__ qkvh)
{
    int p = blockIdx.x * 256 + threadIdx.x;   // 0 .. ROWS*1024-1 (pair id)
    int row = p >> 10;
    int rem = p & 1023;
    int n = row & (NN - 1);
    int half = rem >> 9;                      // 0: q, 1: k
    int pr = rem & 511;
    int i = pr & 31;                          // pair index within head
    int col = half * DD + 2 * pr;
    // theta^(-2i/64) = 2^(-i * log2(10000)/32)
    float inv = exp2f(-(float)i * 0.41524101186f);
    float ang = (float)n * inv;
    float s = sinf(ang), c = cosf(ang);
    float* ptr = qkvh + (size_t)row * QKVH_COLS + col;
    float x0 = ptr[0], x1 = ptr[1];
    ptr[0] = x0 * c - x1 * s;
    ptr[1] = x1 * c + x0 * s;
}

// ---------------------------------------------------------------------------
// Fused causal attention with lookahead modulation.
// Block = (b, h, 64-row q tile). 256 threads (16x16), 4x4 per thread.
// scores = (q.k)*SCALE - silu((hk.k) * (q.hk) * SCALE); causal softmax;
// y = W.v ; o = y - sigmoid(alpha_h) * (hv.y) * hv
// Output written over the q region of qkvh (dead after this kernel).
// ---------------------------------------------------------------------------
__global__ __launch_bounds__(256)
void attn_kernel(float* __restrict__ qkvh, const float* __restrict__ alpha)
{
    __shared__ float Qs[64 * 64], HKs[64 * 64], Ks[64 * 64], Vs[64 * 64], Ws[64 * 64];
    __shared__ float qhk_s[64];

    const int qt = blockIdx.x & 31;          // q tile
    const int bh = blockIdx.x >> 5;
    const int b = bh >> 4, h = bh & 15;
    const int tid = threadIdx.x;
    const int ty = tid >> 4, tx = tid & 15;

    float* base = qkvh + (size_t)b * NN * QKVH_COLS;
    const int qcol = h * DH, kcol = DD + h * DH, vcol = 2 * DD + h * DH;
    const int hkcol = 3 * DD + h * DH, hvcol = 4 * DD + h * DH;

    // ---- load Q, HK tiles (rows qt*64..)
    {
        int r0 = tid >> 4, c4 = tid & 15;
#pragma unroll
        for (int rr = 0; rr < 4; ++rr) {
            int row = rr * 16 + r0;
            size_t g = (size_t)(qt * 64 + row) * QKVH_COLS;
            ((float4*)Qs)[row * 16 + sw16(c4, row)] = *(const float4*)&base[g + qcol + 4 * c4];
            ((float4*)HKs)[row * 16 + sw16(c4, row)] = *(const float4*)&base[g + hkcol + 4 * c4];
        }
    }
    __syncthreads();
    // ---- qhk[r] = q[r] . hk[r]
#pragma unroll
    for (int i = 0; i < 4; ++i) {
        int r = 4 * ty + i;
        float4 q4 = ((float4*)Qs)[r * 16 + sw16(tx, r)];
        float4 h4 = ((float4*)HKs)[r * 16 + sw16(tx, r)];
        float p = q4.x * h4.x + q4.y * h4.y + q4.z * h4.z + q4.w * h4.w;
        p += __shfl_xor(p, 1); p += __shfl_xor(p, 2);
        p += __shfl_xor(p, 4); p += __shfl_xor(p, 8);
        if (tx == 0) qhk_s[r] = p;
    }

    float m_r[4], l_r[4], y[4][4];
#pragma unroll
    for (int i = 0; i < 4; ++i) {
        m_r[i] = -INFINITY; l_r[i] = 0.f;
#pragma unroll
        for (int j = 0; j < 4; ++j) y[i][j] = 0.f;
    }
    const float sig_a = 1.f / (1.f + __expf(-alpha[h]));

    for (int kt = 0; kt <= qt; ++kt) {
        __syncthreads();   // previous PV done before K/V/W overwrite
        {
            int r0 = tid >> 4, c4 = tid & 15;
#pragma unroll
            for (int rr = 0; rr < 4; ++rr) {
                int row = rr * 16 + r0;
                size_t g = (size_t)(kt * 64 + row) * QKVH_COLS;
                ((float4*)Ks)[row * 16 + sw16(c4, row)] = *(const float4*)&base[g + kcol + 4 * c4];
                ((float4*)Vs)[row * 16 + sw16(c4, row)] = *(const float4*)&base[g + vcol + 4 * c4];
            }
        }
        __syncthreads();

        // ---- S = Q.K^T and HKK = HK.K^T (4x4 per thread)
        float sqk[4][4], shk[4][4];
#pragma unroll
        for (int i = 0; i < 4; ++i)
#pragma unroll
            for (int j = 0; j < 4; ++j) { sqk[i][j] = 0.f; shk[i][j] = 0.f; }

#pragma unroll
        for (int k4 = 0; k4 < 16; ++k4) {
            float4 kf[4];
#pragma unroll
            for (int j = 0; j < 4; ++j)
                kf[j] = ((float4*)Ks)[(4 * tx + j) * 16 + ((k4 ^ tx) & 15)];
#pragma unroll
            for (int i = 0; i < 4; ++i) {
                int r = 4 * ty + i;
                float4 qf = ((float4*)Qs)[r * 16 + ((k4 ^ ty) & 15)];
                float4 hf = ((float4*)HKs)[r * 16 + ((k4 ^ ty) & 15)];
#pragma unroll
                for (int j = 0; j < 4; ++j) {
                    sqk[i][j] += qf.x * kf[j].x + qf.y * kf[j].y + qf.z * kf[j].z + qf.w * kf[j].w;
                    shk[i][j] += hf.x * kf[j].x + hf.y * kf[j].y + hf.z * kf[j].z + hf.w * kf[j].w;
                }
            }
        }

        // ---- combine scores + online softmax (row group = 16 lanes)
        const bool diag = (kt == qt);
#pragma unroll
        for (int i = 0; i < 4; ++i) {
            const int r = 4 * ty + i;
            const float qh = qhk_s[r] * SCALE;
            float wrow[4];
#pragma unroll
            for (int j = 0; j < 4; ++j) {
                float z = shk[i][j] * qh;
                float sil = z / (1.f + __expf(-z));
                float s = sqk[i][j] * SCALE - sil;
                if (diag && (4 * tx + j) > r) s = -INFINITY;
                wrow[j] = s;
            }
            float mx = fmaxf(fmaxf(wrow[0], wrow[1]), fmaxf(wrow[2], wrow[3]));
            mx = fmaxf(mx, __shfl_xor(mx, 1)); mx = fmaxf(mx, __shfl_xor(mx, 2));
            mx = fmaxf(mx, __shfl_xor(mx, 4)); mx = fmaxf(mx, __shfl_xor(mx, 8));
            const float mnew = fmaxf(m_r[i], mx);
            const float scl = __expf(m_r[i] - mnew);
            m_r[i] = mnew;
            float rs = 0.f;
#pragma unroll
            for (int j = 0; j < 4; ++j) { wrow[j] = __expf(wrow[j] - mnew); rs += wrow[j]; }
            rs += __shfl_xor(rs, 1); rs += __shfl_xor(rs, 2);
            rs += __shfl_xor(rs, 4); rs += __shfl_xor(rs, 8);
            l_r[i] = l_r[i] * scl + rs;
#pragma unroll
            for (int j = 0; j < 4; ++j) y[i][j] *= scl;
#pragma unroll
            for (int j = 0; j < 4; ++j) sqk[i][j] = wrow[j];   // stash W
        }

        // ---- write W^T to LDS (Ws[m][r] layout, swizzled)
#pragma unroll
        for (int j = 0; j < 4; ++j) {
            int m = 4 * tx + j;
            ((float4*)Ws)[m * 16 + ((ty ^ (m & 15)) & 15)] =
                make_float4(sqk[0][j], sqk[1][j], sqk[2][j], sqk[3][j]);
        }
        __syncthreads();

        // ---- y += W . V
#pragma unroll
        for (int m = 0; m < 64; ++m) {
            float4 wv = ((float4*)Ws)[m * 16 + ((ty ^ (m & 15)) & 15)];
            float4 vv = ((float4*)Vs)[m * 16 + sw16(tx, m)];
            y[0][0] = fmaf(wv.x, vv.x, y[0][0]); y[0][1] = fmaf(wv.x, vv.y, y[0][1]);
            y[0][2] = fmaf(wv.x, vv.z, y[0][2]); y[0][3] = fmaf(wv.x, vv.w, y[0][3]);
            y[1][0] = fmaf(wv.y, vv.x, y[1][0]); y[1][1] = fmaf(wv.y, vv.y, y[1][1]);
            y[1][2] = fmaf(wv.y, vv.z, y[1][2]); y[1][3] = fmaf(wv.y, vv.w, y[1][3]);
            y[2][0] = fmaf(wv.z, vv.x, y[2][0]); y[2][1] = fmaf(wv.z, vv.y, y[2][1]);
            y[2][2] = fmaf(wv.z, vv.z, y[2][2]); y[2][3] = fmaf(wv.z, vv.w, y[2][3]);
            y[3][0] = fmaf(wv.w, vv.x, y[3][0]); y[3][1] = fmaf(wv.w, vv.y, y[3][1]);
            y[3][2] = fmaf(wv.w, vv.z, y[3][2]); y[3][3] = fmaf(wv.w, vv.w, y[3][3]);
        }
    }

    // ---- epilogue: normalize, lookahead correction, store over q region
#pragma unroll
    for (int i = 0; i < 4; ++i) {
        const int r = 4 * ty + i;
        const int grow = qt * 64 + r;
        const float inv_l = 1.f / l_r[i];
        const float4 hv4 = *(const float4*)&base[(size_t)grow * QKVH_COLS + hvcol + 4 * tx];
        float o0 = y[i][0] * inv_l, o1 = y[i][1] * inv_l;
        float o2 = y[i][2] * inv_l, o3 = y[i][3] * inv_l;
        float md = o0 * hv4.x + o1 * hv4.y + o2 * hv4.z + o3 * hv4.w;
        md += __shfl_xor(md, 1); md += __shfl_xor(md, 2);
        md += __shfl_xor(md, 4); md += __shfl_xor(md, 8);
        const float f = sig_a * md;
        o0 -= f * hv4.x; o1 -= f * hv4.y; o2 -= f * hv4.z; o3 -= f * hv4.w;
        *(float4*)&base[(size_t)grow * QKVH_COLS + qcol + 4 * tx] = make_float4(o0, o1, o2, o3);
    }
}

// ---------------------------------------------------------------------------
extern "C" void kernel_launch(void* const* d_in, const int* in_sizes, int n_in,
                              void* d_out, int out_size, void* d_ws, size_t ws_size,
                              hipStream_t stream)
{
    const float* x     = (const float*)d_in[0];
    const float* w_qkv = (const float*)d_in[1];
    const float* w_hkv = (const float*)d_in[2];
    const float* w_out = (const float*)d_in[3];
    const float* b_out = (const float*)d_in[4];
    const float* alpha = (const float*)d_in[5];
    float* out  = (float*)d_out;
    float* qkvh = (float*)d_ws;               // 4096 x 5120 fp32 = 83.9 MB

    // 1) x @ [w_qkv | w_hkv] -> qkvh
    gemm128<<<dim3(QKVH_COLS / 128, ROWS / 128), 256, 0, stream>>>(
        x, DD, w_qkv, 3 * DD, w_hkv, 2 * DD, 3 * DD, nullptr, qkvh, QKVH_COLS, DD);

    // 2) RoPE in place on q,k
    rope_kernel<<<(ROWS * 1024) / 256, 256, 0, stream>>>(qkvh);

    // 3) fused attention (writes output over q region of qkvh)
    attn_kernel<<<dim3(BB * HH * (NN / 64)), 256, 0, stream>>>(qkvh, alpha);

    // 4) attn_out @ w_out + b_out -> d_out   (A = q region, lda = 5120)
    gemm128<<<dim3(DD / 128, ROWS / 128), 256, 0, stream>>>(
        qkvh, QKVH_COLS, w_out, DD, w_out, DD, 1 << 30, b_out, out, DD, DD);
}

// Round 2
// 303.028 us; speedup vs baseline: 11.1713x; 11.1713x over previous
//
#include <hip/hip_runtime.h>
#include <math.h>

typedef unsigned int u32;
typedef unsigned short u16;
typedef __attribute__((ext_vector_type(4))) float f32x4;
typedef __attribute__((ext_vector_type(8))) short s16x8;   // 8 bf16 = 4 VGPRs (MFMA A/B frag)

#define BB 2
#define NN 2048
#define DD 1024
#define HH 16
#define ROWS 4096
#define QC 5120            // qkvh cols: q|k|v|hk|hv
#define SCALE 0.125f

__device__ __forceinline__ u16 f2bf(float x) {
    u32 u = __float_as_uint(x);
    return (u16)((u + 0x7FFFu + ((u >> 16) & 1u)) >> 16);
}
__device__ __forceinline__ float bf2f(u16 h) {
    return __uint_as_float(((u32)h) << 16);
}

// ---------------------------------------------------------------------------
// Prep: x (f32) -> bf16
// ---------------------------------------------------------------------------
__global__ __launch_bounds__(256) void convert_x(const float* __restrict__ x,
                                                 uint4* __restrict__ xb)
{
    int t = blockIdx.x * 256 + threadIdx.x;   // 8 floats each
    const float4 a = ((const float4*)x)[2 * t];
    const float4 b = ((const float4*)x)[2 * t + 1];
    uint4 o;
    o.x = f2bf(a.x) | ((u32)f2bf(a.y) << 16);
    o.y = f2bf(a.z) | ((u32)f2bf(a.w) << 16);
    o.z = f2bf(b.x) | ((u32)f2bf(b.y) << 16);
    o.w = f2bf(b.z) | ((u32)f2bf(b.w) << 16);
    xb[t] = o;
}

// ---------------------------------------------------------------------------
// Prep: weights -> wT[c][k] bf16 (B^T layout). Rows 0..5119 = [wqkv|whkv],
// rows 5120..6143 = w_out^T. Tiled 64x64 transpose via padded LDS.
// ---------------------------------------------------------------------------
__global__ __launch_bounds__(256) void transpose_w(const float* __restrict__ wqkv,
                                                   const float* __restrict__ whkv,
                                                   const float* __restrict__ wout,
                                                   u16* __restrict__ wT)
{
    __shared__ float T[64][65];
    const int bc = blockIdx.x;           // 0..95
    const int k0 = blockIdx.y * 64;
    const int c0 = bc * 64;              // wT row base
    const float* src; int stride; int csrc;
    if (bc < 48)      { src = wqkv; stride = 3072; csrc = c0; }
    else if (bc < 80) { src = whkv; stride = 2048; csrc = c0 - 3072; }
    else              { src = wout; stride = 1024; csrc = c0 - 5120; }
    const int t = threadIdx.x;
    const int r = t >> 4, c4 = t & 15;
#pragma unroll
    for (int i = 0; i < 4; ++i) {
        int kk = r + 16 * i;
        float4 v = *(const float4*)&src[(size_t)(k0 + kk) * stride + csrc + 4 * c4];
        T[kk][4 * c4 + 0] = v.x; T[kk][4 * c4 + 1] = v.y;
        T[kk][4 * c4 + 2] = v.z; T[kk][4 * c4 + 3] = v.w;
    }
    __syncthreads();
#pragma unroll
    for (int i = 0; i < 4; ++i) {
        int cc = r + 16 * i;
        u32 lo = f2bf(T[4 * c4 + 0][cc]) | ((u32)f2bf(T[4 * c4 + 1][cc]) << 16);
        u32 hi = f2bf(T[4 * c4 + 2][cc]) | ((u32)f2bf(T[4 * c4 + 3][cc]) << 16);
        *(uint2*)&wT[(size_t)(c0 + cc) * 1024 + k0 + 4 * c4] = make_uint2(lo, hi);
    }
}

// ---------------------------------------------------------------------------
// Prep: rope table  tab[n][0..31]=cos, tab[n][32..63]=sin
// ---------------------------------------------------------------------------
__global__ __launch_bounds__(256) void rope_table(float* __restrict__ tab)
{
    int t = blockIdx.x * 256 + threadIdx.x;   // 2048*64
    int n = t >> 6, col = t & 63, i = col & 31;
    float ang = (float)n * exp2f(-(float)i * 0.41524101186092029f); // 10000^(-i/32)
    tab[t] = (col < 32) ? cosf(ang) : sinf(ang);
}

// ---------------------------------------------------------------------------
// RoPE in place on bf16 qkvh cols 0..2047 (q and k), interleaved pairs
// ---------------------------------------------------------------------------
__global__ __launch_bounds__(256) void rope_apply(u16* __restrict__ qkvh,
                                                  const float* __restrict__ tab)
{
    int t = blockIdx.x * 256 + threadIdx.x;   // ROWS*1024 pairs
    int row = t >> 10, p = t & 1023;
    int n = row & (NN - 1);
    int i = p & 31;
    float cc = tab[(n << 6) + i], ss = tab[(n << 6) + 32 + i];
    u32* ptr = (u32*)(qkvh + (size_t)row * QC + 2 * p);
    u32 v = *ptr;
    float x0 = bf2f((u16)v), x1 = bf2f((u16)(v >> 16));
    float r0 = x0 * cc - x1 * ss;
    float r1 = x1 * cc + x0 * ss;
    *ptr = (u32)f2bf(r0) | ((u32)f2bf(r1) << 16);
}

// ---------------------------------------------------------------------------
// bf16 MFMA GEMM: C[M][N] = A[M][K] @ B^T  (B given as wT[N][K])
// 128x128 tile, BK=64, 4 waves (2x2), 4x4 16x16 frags per wave.
// BF16_OUT=1: bf16 C; else f32 C + bias.
// ---------------------------------------------------------------------------
template <int BF16_OUT>
__global__ __launch_bounds__(256, 2) void gemm_bf16(
    const u16* __restrict__ A, int lda,
    const u16* __restrict__ B, int ldb,
    void* __restrict__ C, int ldc,
    const float* __restrict__ bias, int K)
{
    __shared__ char As[128 * 128];   // [128][64] bf16, 16B-chunk XOR swizzle
    __shared__ char Bs[128 * 128];
    const int tid = threadIdx.x;
    const int lane = tid & 63, w = tid >> 6;
    const int g = lane >> 4, c = lane & 15;
    const int wr = w >> 1, wc = w & 1;
    const int rb0 = blockIdx.y * 128, cb0 = blockIdx.x * 128;

    f32x4 acc[4][4];
#pragma unroll
    for (int i = 0; i < 4; ++i)
#pragma unroll
        for (int j = 0; j < 4; ++j) {
            acc[i][j][0] = 0.f; acc[i][j][1] = 0.f; acc[i][j][2] = 0.f; acc[i][j][3] = 0.f;
        }

    for (int k0 = 0; k0 < K; k0 += 64) {
        __syncthreads();
#pragma unroll
        for (int r = 0; r < 4; ++r) {
            int idx = tid + 256 * r;
            int row = idx >> 3, ch = idx & 7;
            uint4 va = *(const uint4*)&A[(size_t)(rb0 + row) * lda + k0 + ch * 8];
            *(uint4*)(As + row * 128 + ((ch ^ (row & 7)) << 4)) = va;
            uint4 vb = *(const uint4*)&B[(size_t)(cb0 + row) * ldb + k0 + ch * 8];
            *(uint4*)(Bs + row * 128 + ((ch ^ (row & 7)) << 4)) = vb;
        }
        __syncthreads();
#pragma unroll
        for (int kk = 0; kk < 2; ++kk) {
            s16x8 a[4], b[4];
#pragma unroll
            for (int rb = 0; rb < 4; ++rb) {
                int row = wr * 64 + rb * 16 + c;
                a[rb] = *(const s16x8*)(As + row * 128 + ((((kk << 2) + g) ^ (row & 7)) << 4));
            }
#pragma unroll
            for (int cb = 0; cb < 4; ++cb) {
                int row = wc * 64 + cb * 16 + c;
                b[cb] = *(const s16x8*)(Bs + row * 128 + ((((kk << 2) + g) ^ (row & 7)) << 4));
            }
#pragma unroll
            for (int rb = 0; rb < 4; ++rb)
#pragma unroll
                for (int cb = 0; cb < 4; ++cb)
                    acc[rb][cb] = __builtin_amdgcn_mfma_f32_16x16x32_bf16(a[rb], b[cb], acc[rb][cb], 0, 0, 0);
        }
    }
#pragma unroll
    for (int rb = 0; rb < 4; ++rb) {
#pragma unroll
        for (int cb = 0; cb < 4; ++cb) {
            if (BF16_OUT) {
                uint2 keep = make_uint2(0, 0);
#pragma unroll
                for (int e = 0; e < 4; ++e) {
                    u32 me = f2bf(acc[rb][cb][e]);
                    u32 x1 = (u32)__shfl_xor((int)me, 1);
                    u32 pair = (c & 1) ? ((x1 & 0xffffu) | (me << 16)) : ((me & 0xffffu) | (x1 << 16));
                    u32 x2 = (u32)__shfl_xor((int)pair, 2);
                    u32 q0 = (c & 2) ? x2 : pair;
                    u32 q1 = (c & 2) ? pair : x2;
                    if ((c & 3) == e) keep = make_uint2(q0, q1);
                }
                int row = rb0 + wr * 64 + rb * 16 + g * 4 + (c & 3);
                int col = cb0 + wc * 64 + cb * 16 + (c & ~3);
                *(uint2*)((u16*)C + (size_t)row * ldc + col) = keep;
            } else {
                int col = cb0 + wc * 64 + cb * 16 + c;
                float bv = bias ? bias[col] : 0.f;
#pragma unroll
                for (int e = 0; e < 4; ++e) {
                    int row = rb0 + wr * 64 + rb * 16 + g * 4 + e;
                    ((float*)C)[(size_t)row * ldc + col] = acc[rb][cb][e] + bv;
                }
            }
        }
    }
}

// ---------------------------------------------------------------------------
// Fused lookahead attention (flash-style, bf16 MFMA).
// Block = (b, h, 128 q-rows). 4 waves x 32 rows. KV tiles of 64.
// scores = qk*SCALE - silu(hkk * qhk * SCALE); causal online softmax;
// y = W.v ;  o = y/l - sigmoid(alpha_h)*(hv.(y/l))*hv  -> bf16 attn_out
// ---------------------------------------------------------------------------
__global__ __launch_bounds__(256, 2) void attn(
    const u16* __restrict__ qkvh, const float* __restrict__ alpha,
    u16* __restrict__ attn_out)
{
    __shared__ char bufQ[128 * 128];   // Q, then HV at epilogue
    __shared__ char bufH[128 * 128];   // HK
    __shared__ char bufK[64 * 128];    // K tile
    __shared__ char bufV[64 * 128];    // V^T tile [d][kv]
    __shared__ char bufW[128 * 128];   // P (bf16) per wave rows
    __shared__ float qhk_s[128];

    const int qb = 15 - (blockIdx.x >> 5);   // big tiles dispatched first
    const int bh = blockIdx.x & 31;
    const int b = bh >> 4, h = bh & 15;
    const int tid = threadIdx.x;
    const int lane = tid & 63, w = tid >> 6;
    const int g = lane >> 4, c = lane & 15;

    const u16* base = qkvh + (size_t)b * NN * QC;
    const int q0row = qb * 128;

    {   // stage Q, HK (128x64 each)
        const u16* qsrc = base + (size_t)q0row * QC + h * 64;
        const u16* hsrc = base + (size_t)q0row * QC + 3072 + h * 64;
#pragma unroll
        for (int r = 0; r < 4; ++r) {
            int idx = tid + 256 * r;
            int row = idx >> 3, ch = idx & 7;
            *(uint4*)(bufQ + row * 128 + ((ch ^ (row & 7)) << 4)) =
                *(const uint4*)(qsrc + (size_t)row * QC + ch * 8);
            *(uint4*)(bufH + row * 128 + ((ch ^ (row & 7)) << 4)) =
                *(const uint4*)(hsrc + (size_t)row * QC + ch * 8);
        }
    }
    __syncthreads();

    // hoist Q/HK frags (wave rows w*32..+31)
    s16x8 qf[2][2], hf[2][2];
#pragma unroll
    for (int rb = 0; rb < 2; ++rb)
#pragma unroll
        for (int kk = 0; kk < 2; ++kk) {
            int row = w * 32 + rb * 16 + c;
            int chb = (kk << 2) + g;
            qf[rb][kk] = *(const s16x8*)(bufQ + row * 128 + ((chb ^ (row & 7)) << 4));
            hf[rb][kk] = *(const s16x8*)(bufH + row * 128 + ((chb ^ (row & 7)) << 4));
        }
    // qhk[r] = q[r].hk[r]
#pragma unroll
    for (int rb = 0; rb < 2; ++rb) {
        float s = 0.f;
#pragma unroll
        for (int kk = 0; kk < 2; ++kk)
#pragma unroll
            for (int j = 0; j < 8; ++j)
                s += bf2f((u16)qf[rb][kk][j]) * bf2f((u16)hf[rb][kk][j]);
        s += __shfl_xor(s, 16);
        s += __shfl_xor(s, 32);
        if (lane < 16) qhk_s[w * 32 + rb * 16 + c] = s;
    }
    __syncthreads();
    f32x4 qh4[2];
#pragma unroll
    for (int rb = 0; rb < 2; ++rb) {
        f32x4 t = *(const f32x4*)&qhk_s[w * 32 + rb * 16 + g * 4];
#pragma unroll
        for (int e = 0; e < 4; ++e) qh4[rb][e] = t[e] * SCALE;
    }

    const float sig_a = 1.f / (1.f + __expf(-alpha[h]));

    f32x4 y[2][4], m_r[2], l_r[2];
#pragma unroll
    for (int rb = 0; rb < 2; ++rb) {
#pragma unroll
        for (int e = 0; e < 4; ++e) { m_r[rb][e] = -INFINITY; l_r[rb][e] = 0.f; }
#pragma unroll
        for (int db = 0; db < 4; ++db) {
            y[rb][db][0] = 0.f; y[rb][db][1] = 0.f; y[rb][db][2] = 0.f; y[rb][db][3] = 0.f;
        }
    }

    const int KT = 2 * qb + 2;
    for (int kt = 0; kt < KT; ++kt) {
        __syncthreads();
        {   // stage K (swizzled) and V^T
            const u16* ksrc = base + (size_t)(kt * 64) * QC + 1024 + h * 64;
#pragma unroll
            for (int r = 0; r < 2; ++r) {
                int idx = tid + 256 * r;
                int row = idx >> 3, ch = idx & 7;
                *(uint4*)(bufK + row * 128 + ((ch ^ (row & 7)) << 4)) =
                    *(const uint4*)(ksrc + (size_t)row * QC + ch * 8);
            }
            const u16* vsrc = base + (size_t)(kt * 64) * QC + 2048 + h * 64;
            int rr = tid & 31, ccc = tid >> 5;     // row-pair, 8-elem chunk
            uint4 v0 = *(const uint4*)(vsrc + (size_t)(2 * rr) * QC + ccc * 8);
            uint4 v1 = *(const uint4*)(vsrc + (size_t)(2 * rr + 1) * QC + ccc * 8);
            const u16* p0 = (const u16*)&v0;
            const u16* p1 = (const u16*)&v1;
#pragma unroll
            for (int j = 0; j < 8; ++j) {
                int d = ccc * 8 + j;
                u32 pk = (u32)p0[j] | ((u32)p1[j] << 16);
                *(u32*)(bufV + d * 128 + ((rr * 4) ^ ((d & 7) << 4))) = pk;
            }
        }
        __syncthreads();

        // S = Q.K^T, HKK = HK.K^T
        f32x4 sq[2][4], sh[2][4];
#pragma unroll
        for (int rb = 0; rb < 2; ++rb)
#pragma unroll
            for (int cb = 0; cb < 4; ++cb) {
#pragma unroll
                for (int e = 0; e < 4; ++e) { sq[rb][cb][e] = 0.f; sh[rb][cb][e] = 0.f; }
            }
#pragma unroll
        for (int kk = 0; kk < 2; ++kk) {
            s16x8 kf[4];
#pragma unroll
            for (int cb = 0; cb < 4; ++cb) {
                int row = cb * 16 + c;
                kf[cb] = *(const s16x8*)(bufK + row * 128 + ((((kk << 2) + g) ^ (row & 7)) << 4));
            }
#pragma unroll
            for (int rb = 0; rb < 2; ++rb)
#pragma unroll
                for (int cb = 0; cb < 4; ++cb) {
                    sq[rb][cb] = __builtin_amdgcn_mfma_f32_16x16x32_bf16(qf[rb][kk], kf[cb], sq[rb][cb], 0, 0, 0);
                    sh[rb][cb] = __builtin_amdgcn_mfma_f32_16x16x32_bf16(hf[rb][kk], kf[cb], sh[rb][cb], 0, 0, 0);
                }
        }

        // scores + online softmax (rows: g*4+e within 16-block; cols: c)
        const bool maskt = (kt >= 2 * qb);
#pragma unroll
        for (int rb = 0; rb < 2; ++rb) {
            f32x4 sc[4];
#pragma unroll
            for (int cb = 0; cb < 4; ++cb) {
#pragma unroll
                for (int e = 0; e < 4; ++e) {
                    float z = sh[rb][cb][e] * qh4[rb][e];
                    float sil = z / (1.f + __expf(-z));
                    float v = sq[rb][cb][e] * SCALE - sil;
                    if (maskt) {
                        int qrow = q0row + w * 32 + rb * 16 + g * 4 + e;
                        int kcol = kt * 64 + cb * 16 + c;
                        if (kcol > qrow) v = -INFINITY;
                    }
                    sc[cb][e] = v;
                }
            }
#pragma unroll
            for (int e = 0; e < 4; ++e) {
                float m0 = fmaxf(fmaxf(sc[0][e], sc[1][e]), fmaxf(sc[2][e], sc[3][e]));
                m0 = fmaxf(m0, __shfl_xor(m0, 1));
                m0 = fmaxf(m0, __shfl_xor(m0, 2));
                m0 = fmaxf(m0, __shfl_xor(m0, 4));
                m0 = fmaxf(m0, __shfl_xor(m0, 8));
                float mnew = fmaxf(m_r[rb][e], m0);
                float scl = __expf(m_r[rb][e] - mnew);
                m_r[rb][e] = mnew;
                float rs = 0.f;
#pragma unroll
                for (int cb = 0; cb < 4; ++cb) {
                    float p = __expf(sc[cb][e] - mnew);
                    sc[cb][e] = p;
                    rs += p;
                }
                rs += __shfl_xor(rs, 1); rs += __shfl_xor(rs, 2);
                rs += __shfl_xor(rs, 4); rs += __shfl_xor(rs, 8);
                l_r[rb][e] = l_r[rb][e] * scl + rs;
#pragma unroll
                for (int db = 0; db < 4; ++db) y[rb][db][e] *= scl;
            }
            // pack P -> bufW (wave-local rows; no barrier needed)
#pragma unroll
            for (int cb = 0; cb < 4; ++cb) {
                uint2 keep = make_uint2(0, 0);
#pragma unroll
                for (int e = 0; e < 4; ++e) {
                    u32 me = f2bf(sc[cb][e]);
                    u32 x1 = (u32)__shfl_xor((int)me, 1);
                    u32 pair = (c & 1) ? ((x1 & 0xffffu) | (me << 16)) : ((me & 0xffffu) | (x1 << 16));
                    u32 x2 = (u32)__shfl_xor((int)pair, 2);
                    u32 q0 = (c & 2) ? x2 : pair;
                    u32 q1 = (c & 2) ? pair : x2;
                    if ((c & 3) == e) keep = make_uint2(q0, q1);
                }
                int row = w * 32 + rb * 16 + g * 4 + (c & 3);
                int off = (cb * 32 + ((c >> 2) << 3)) ^ ((row & 7) << 4);
                *(uint2*)(bufW + row * 128 + off) = keep;
            }
        }

        // y += P.V  (A = P from bufW, B = V^T frags from bufV)
#pragma unroll
        for (int kk = 0; kk < 2; ++kk) {
            s16x8 wf[2], vf[4];
#pragma unroll
            for (int rb = 0; rb < 2; ++rb) {
                int row = w * 32 + rb * 16 + c;
                wf[rb] = *(const s16x8*)(bufW + row * 128 + ((((kk << 2) + g) ^ (row & 7)) << 4));
            }
#pragma unroll
            for (int db = 0; db < 4; ++db) {
                int row = db * 16 + c;
                vf[db] = *(const s16x8*)(bufV + row * 128 + ((((kk << 2) + g) ^ (row & 7)) << 4));
            }
#pragma unroll
            for (int rb = 0; rb < 2; ++rb)
#pragma unroll
                for (int db = 0; db < 4; ++db)
                    y[rb][db] = __builtin_amdgcn_mfma_f32_16x16x32_bf16(wf[rb], vf[db], y[rb][db], 0, 0, 0);
        }
    }

    // epilogue: stage HV into bufQ, normalize, lookahead correction, store
    __syncthreads();
    {
        const u16* hvsrc = base + (size_t)q0row * QC + 4096 + h * 64;
#pragma unroll
        for (int r = 0; r < 4; ++r) {
            int idx = tid + 256 * r;
            int row = idx >> 3, ch = idx & 7;
            *(uint4*)(bufQ + row * 128 + ((ch ^ (row & 7)) << 4)) =
                *(const uint4*)(hvsrc + (size_t)row * QC + ch * 8);
        }
    }
    __syncthreads();

#pragma unroll
    for (int rb = 0; rb < 2; ++rb) {
        float hvv[4][4];
#pragma unroll
        for (int e = 0; e < 4; ++e) {
            int row = w * 32 + rb * 16 + g * 4 + e;
#pragma unroll
            for (int db = 0; db < 4; ++db) {
                int off = (db * 32 + c * 2) ^ ((row & 7) << 4);
                hvv[db][e] = bf2f(*(const u16*)(bufQ + row * 128 + off));
            }
        }
#pragma unroll
        for (int e = 0; e < 4; ++e) {
            float inv_l = 1.f / l_r[rb][e];
            float s = 0.f;
#pragma unroll
            for (int db = 0; db < 4; ++db) {
                float yn = y[rb][db][e] * inv_l;
                y[rb][db][e] = yn;
                s += yn * hvv[db][e];
            }
            s += __shfl_xor(s, 1); s += __shfl_xor(s, 2);
            s += __shfl_xor(s, 4); s += __shfl_xor(s, 8);
            float f = s * sig_a;
            int grow = b * NN + q0row + w * 32 + rb * 16 + g * 4 + e;
#pragma unroll
            for (int db = 0; db < 4; ++db) {
                float o = y[rb][db][e] - f * hvv[db][e];
                attn_out[(size_t)grow * DD + h * 64 + db * 16 + c] = f2bf(o);
            }
        }
    }
}

// ---------------------------------------------------------------------------
extern "C" void kernel_launch(void* const* d_in, const int* in_sizes, int n_in,
                              void* d_out, int out_size, void* d_ws, size_t ws_size,
                              hipStream_t stream)
{
    const float* x     = (const float*)d_in[0];
    const float* w_qkv = (const float*)d_in[1];
    const float* w_hkv = (const float*)d_in[2];
    const float* w_out = (const float*)d_in[3];
    const float* b_out = (const float*)d_in[4];
    const float* alpha = (const float*)d_in[5];

    char* ws = (char*)d_ws;
    u16*   qkvh = (u16*)ws;                       // 4096x5120 bf16 = 41,943,040 B
    uint4* xb   = (uint4*)(ws + 41943040);        // 4096x1024 bf16 =  8,388,608 B
    u16*   wT   = (u16*)(ws + 50331648);          // 6144x1024 bf16 = 12,582,912 B
    u16*   aout = (u16*)(ws + 62914560);          // 4096x1024 bf16 =  8,388,608 B
    float* tab  = (float*)(ws + 71303168);        // 2048x64 f32    =    524,288 B

    convert_x<<<2048, 256, 0, stream>>>(x, xb);
    transpose_w<<<dim3(96, 16), 256, 0, stream>>>(w_qkv, w_hkv, w_out, wT);
    rope_table<<<512, 256, 0, stream>>>(tab);

    // 1) qkvh = x @ [w_qkv | w_hkv]   (bf16 out)
    gemm_bf16<1><<<dim3(40, 32), 256, 0, stream>>>(
        (const u16*)xb, 1024, wT, 1024, qkvh, QC, nullptr, 1024);

    // 2) RoPE on q,k
    rope_apply<<<16384, 256, 0, stream>>>(qkvh, tab);

    // 3) fused attention -> aout (bf16)
    attn<<<512, 256, 0, stream>>>(qkvh, alpha, aout);

    // 4) out = aout @ w_out + b_out   (f32 out)
    gemm_bf16<0><<<dim3(8, 32), 256, 0, stream>>>(
        aout, 1024, wT + 5120 * 1024, 1024, d_out, 1024, b_out, 1024);
}

// Round 4
// 212.054 us; speedup vs baseline: 15.9639x; 1.4290x over previous
//
#include <hip/hip_runtime.h>
#include <math.h>

typedef unsigned int u32;
typedef unsigned short u16;
typedef __attribute__((ext_vector_type(4))) float f32x4;
typedef __attribute__((ext_vector_type(8))) short s16x8;   // 8 bf16 (MFMA A/B frag)

#define BB 2
#define NN 2048
#define DD 1024
#define HH 16
#define ROWS 4096
#define QC 5120            // qkvh cols: q|k|v|hk|hv
#define SCALE 0.125f

__device__ __forceinline__ u16 f2bf(float x) {
    u32 u = __float_as_uint(x);
    return (u16)((u + 0x7FFFu + ((u >> 16) & 1u)) >> 16);
}
__device__ __forceinline__ float bf2f(u16 h) {
    return __uint_as_float(((u32)h) << 16);
}
__device__ __forceinline__ u32 cvtpk(float lo, float hi) {
    u32 r;
    asm("v_cvt_pk_bf16_f32 %0, %1, %2" : "=v"(r) : "v"(lo), "v"(hi));
    return r;
}
__device__ __forceinline__ void gload16(const void* g, void* l) {
    __builtin_amdgcn_global_load_lds(
        (const __attribute__((address_space(1))) unsigned int*)g,
        (__attribute__((address_space(3))) unsigned int*)l, 16, 0, 0);
}

// Transpose a 64x64 V tile into Vt[d][kv] (bf16-pair packed, XOR-swizzled
// chunks). Thread (srow = tid>>3, sch = tid&7) holds V[srow][sch*8..+7] in
// vreg; partner lane (srow^1, same sch) supplies the adjacent kv row.
// Even srow writes dims sch*8..+3, odd writes sch*8+4..+7, each for the kv
// pair (2s, 2s+1), s = srow>>1. Slot address: d*128 + ((s>>2)^(d&7))*16 +
// (s&3)*4  — bijective, every (d,s) written exactly once.
__device__ __forceinline__ void vt_write(char* vbb, uint4 vreg, int srow, int sch)
{
    uint4 oth;
    oth.x = (u32)__shfl_xor((int)vreg.x, 8); oth.y = (u32)__shfl_xor((int)vreg.y, 8);
    oth.z = (u32)__shfl_xor((int)vreg.z, 8); oth.w = (u32)__shfl_xor((int)vreg.w, 8);
    const bool odd = (srow & 1);
    u32 ma = odd ? vreg.z : vreg.x, mb = odd ? vreg.w : vreg.y;
    u32 oa = odd ? oth.z : oth.x,  ob = odd ? oth.w : oth.y;
    u32 ea = odd ? oa : ma, eb = odd ? ob : mb;   // even kv row (2s)
    u32 da = odd ? ma : oa, db = odd ? mb : ob;   // odd  kv row (2s+1)
    u32 pk0 = (ea & 0xffffu) | (da << 16);
    u32 pk1 = (ea >> 16)     | (db & 0u) | (da & 0xffff0000u);
    u32 pk2 = (eb & 0xffffu) | (db << 16);
    u32 pk3 = (eb >> 16)     | (db & 0xffff0000u);
    const int s = srow >> 1;
    const int d0 = sch * 8 + (odd ? 4 : 0);
    *(u32*)(vbb + (d0 + 0) * 128 + ((((s >> 2) ^ ((d0 + 0) & 7)) << 4)) + (s & 3) * 4) = pk0;
    *(u32*)(vbb + (d0 + 1) * 128 + ((((s >> 2) ^ ((d0 + 1) & 7)) << 4)) + (s & 3) * 4) = pk1;
    *(u32*)(vbb + (d0 + 2) * 128 + ((((s >> 2) ^ ((d0 + 2) & 7)) << 4)) + (s & 3) * 4) = pk2;
    *(u32*)(vbb + (d0 + 3) * 128 + ((((s >> 2) ^ ((d0 + 3) & 7)) << 4)) + (s & 3) * 4) = pk3;
}

// ---------------------------------------------------------------------------
// Prep: x (f32) -> bf16
// ---------------------------------------------------------------------------
__global__ __launch_bounds__(256) void convert_x(const float* __restrict__ x,
                                                 uint4* __restrict__ xb)
{
    int t = blockIdx.x * 256 + threadIdx.x;
    const float4 a = ((const float4*)x)[2 * t];
    const float4 b = ((const float4*)x)[2 * t + 1];
    uint4 o;
    o.x = f2bf(a.x) | ((u32)f2bf(a.y) << 16);
    o.y = f2bf(a.z) | ((u32)f2bf(a.w) << 16);
    o.z = f2bf(b.x) | ((u32)f2bf(b.y) << 16);
    o.w = f2bf(b.z) | ((u32)f2bf(b.w) << 16);
    xb[t] = o;
}

// ---------------------------------------------------------------------------
// Prep: weights -> wT[c][k] bf16 (rows 0..5119 = [wqkv|whkv], 5120.. = w_out^T)
// ---------------------------------------------------------------------------
__global__ __launch_bounds__(256) void transpose_w(const float* __restrict__ wqkv,
                                                   const float* __restrict__ whkv,
                                                   const float* __restrict__ wout,
                                                   u16* __restrict__ wT)
{
    __shared__ float T[64][65];
    const int bc = blockIdx.x;
    const int k0 = blockIdx.y * 64;
    const int c0 = bc * 64;
    const float* src; int stride; int csrc;
    if (bc < 48)      { src = wqkv; stride = 3072; csrc = c0; }
    else if (bc < 80) { src = whkv; stride = 2048; csrc = c0 - 3072; }
    else              { src = wout; stride = 1024; csrc = c0 - 5120; }
    const int t = threadIdx.x;
    const int r = t >> 4, c4 = t & 15;
#pragma unroll
    for (int i = 0; i < 4; ++i) {
        int kk = r + 16 * i;
        float4 v = *(const float4*)&src[(size_t)(k0 + kk) * stride + csrc + 4 * c4];
        T[kk][4 * c4 + 0] = v.x; T[kk][4 * c4 + 1] = v.y;
        T[kk][4 * c4 + 2] = v.z; T[kk][4 * c4 + 3] = v.w;
    }
    __syncthreads();
#pragma unroll
    for (int i = 0; i < 4; ++i) {
        int cc = r + 16 * i;
        u32 lo = f2bf(T[4 * c4 + 0][cc]) | ((u32)f2bf(T[4 * c4 + 1][cc]) << 16);
        u32 hi = f2bf(T[4 * c4 + 2][cc]) | ((u32)f2bf(T[4 * c4 + 3][cc]) << 16);
        *(uint2*)&wT[(size_t)(c0 + cc) * 1024 + k0 + 4 * c4] = make_uint2(lo, hi);
    }
}

// ---------------------------------------------------------------------------
// Prep: rope table  tab[n][0..31]=cos, tab[n][32..63]=sin
// ---------------------------------------------------------------------------
__global__ __launch_bounds__(256) void rope_table(float* __restrict__ tab)
{
    int t = blockIdx.x * 256 + threadIdx.x;
    int n = t >> 6, col = t & 63, i = col & 31;
    float ang = (float)n * exp2f(-(float)i * 0.41524101186092029f);
    tab[t] = (col < 32) ? cosf(ang) : sinf(ang);
}

// ---------------------------------------------------------------------------
// RoPE in place on K region only (cols 1024..2047)
// ---------------------------------------------------------------------------
__global__ __launch_bounds__(256) void rope_k(u16* __restrict__ qkvh,
                                              const float* __restrict__ tab)
{
    int t = blockIdx.x * 256 + threadIdx.x;   // ROWS*512 pairs
    int row = t >> 9, p = t & 511;
    int n = row & (NN - 1);
    int i = p & 31;
    float cc = tab[(n << 6) + i], ss = tab[(n << 6) + 32 + i];
    u32* ptr = (u32*)(qkvh + (size_t)row * QC + 1024 + 2 * p);
    u32 v = *ptr;
    float x0 = bf2f((u16)v), x1 = bf2f((u16)(v >> 16));
    float r0 = x0 * cc - x1 * ss;
    float r1 = x1 * cc + x0 * ss;
    *ptr = (u32)f2bf(r0) | ((u32)f2bf(r1) << 16);
}

// ---------------------------------------------------------------------------
// bf16 MFMA GEMM: C[M][N] = A[M][K] @ B^T (B = wT[N][K]); global_load_lds
// staging (pre-swizzled source, linear LDS dest). 128x128 tile, BK=64.
// ---------------------------------------------------------------------------
template <int BF16_OUT>
__global__ __launch_bounds__(256, 2) void gemm_bf16(
    const u16* __restrict__ A, int lda,
    const u16* __restrict__ B, int ldb,
    void* __restrict__ C, int ldc,
    const float* __restrict__ bias, int K)
{
    __shared__ u16 As[128 * 64];   // 16KB, [row][64k] bf16; chunk cl at cl^(row&7)
    __shared__ u16 Bs[128 * 64];
    const int tid = threadIdx.x;
    const int lane = tid & 63, w = tid >> 6;
    const int g = lane >> 4, c = lane & 15;
    const int wr = w >> 1, wc = w & 1;
    const int rb0 = blockIdx.y * 128, cb0 = blockIdx.x * 128;

    f32x4 acc[4][4];
#pragma unroll
    for (int i = 0; i < 4; ++i)
#pragma unroll
        for (int j = 0; j < 4; ++j) {
            acc[i][j][0] = 0.f; acc[i][j][1] = 0.f; acc[i][j][2] = 0.f; acc[i][j][3] = 0.f;
        }

    const int srow = tid >> 3, sch = tid & 7;
    const int scol = ((sch ^ (srow & 7)) * 8);
    const u16* asrc = A + (size_t)(rb0 + srow) * lda + scol;
    const u16* bsrc = B + (size_t)(cb0 + srow) * ldb + scol;

    for (int k0 = 0; k0 < K; k0 += 64) {
        __syncthreads();
#pragma unroll
        for (int r = 0; r < 4; ++r) {
            gload16(asrc + (size_t)(32 * r) * lda + k0, (char*)As + r * 4096 + w * 1024);
            gload16(bsrc + (size_t)(32 * r) * ldb + k0, (char*)Bs + r * 4096 + w * 1024);
        }
        __syncthreads();
#pragma unroll
        for (int kk = 0; kk < 2; ++kk) {
            s16x8 a[4], b[4];
#pragma unroll
            for (int rb = 0; rb < 4; ++rb) {
                int row = wr * 64 + rb * 16 + c;
                a[rb] = *(const s16x8*)((const char*)As + row * 128 + ((((kk << 2) + g) ^ (row & 7)) << 4));
            }
#pragma unroll
            for (int cb = 0; cb < 4; ++cb) {
                int row = wc * 64 + cb * 16 + c;
                b[cb] = *(const s16x8*)((const char*)Bs + row * 128 + ((((kk << 2) + g) ^ (row & 7)) << 4));
            }
#pragma unroll
            for (int rb = 0; rb < 4; ++rb)
#pragma unroll
                for (int cb = 0; cb < 4; ++cb)
                    acc[rb][cb] = __builtin_amdgcn_mfma_f32_16x16x32_bf16(a[rb], b[cb], acc[rb][cb], 0, 0, 0);
        }
    }
#pragma unroll
    for (int rb = 0; rb < 4; ++rb) {
#pragma unroll
        for (int cb = 0; cb < 4; ++cb) {
            if (BF16_OUT) {
                uint2 keep = make_uint2(0, 0);
#pragma unroll
                for (int e = 0; e < 4; ++e) {
                    u32 me = f2bf(acc[rb][cb][e]);
                    u32 x1 = (u32)__shfl_xor((int)me, 1);
                    u32 pair = (c & 1) ? ((x1 & 0xffffu) | (me << 16)) : ((me & 0xffffu) | (x1 << 16));
                    u32 x2 = (u32)__shfl_xor((int)pair, 2);
                    u32 q0 = (c & 2) ? x2 : pair;
                    u32 q1 = (c & 2) ? pair : x2;
                    if ((c & 3) == e) keep = make_uint2(q0, q1);
                }
                int row = rb0 + wr * 64 + rb * 16 + g * 4 + (c & 3);
                int col = cb0 + wc * 64 + cb * 16 + (c & ~3);
                *(uint2*)((u16*)C + (size_t)row * ldc + col) = keep;
            } else {
                int col = cb0 + wc * 64 + cb * 16 + c;
                float bv = bias ? bias[col] : 0.f;
#pragma unroll
                for (int e = 0; e < 4; ++e) {
                    int row = rb0 + wr * 64 + rb * 16 + g * 4 + e;
                    ((float*)C)[(size_t)row * ldc + col] = acc[rb][cb][e] + bv;
                }
            }
        }
    }
}

// ---------------------------------------------------------------------------
// Fused lookahead attention, swapped-layout (lane owns q-row = lane&15).
// Block = (b,h,128 q rows), 8 waves x 16 rows, KV tiles of 64, dbuf K/V^T.
// K frag rows permuted (A row r of block kb <- K row 8*(r>>2)+(r&3)+4*(kb&1)
// +32*(kb>>1)) so softmax'd P lands directly in the PV B-fragment layout
// (j = e + 4*(kb&1)): zero-shuffle P, no LDS P buffer.
// ---------------------------------------------------------------------------
__global__ __launch_bounds__(512, 4) void attn(
    const u16* __restrict__ qkvh, const float* __restrict__ alpha,
    const float* __restrict__ tab, u16* __restrict__ aout)
{
    __shared__ u16 Kb[2][64 * 64];   // 8 KB each: [kvrow][64d], chunk cl at cl^f(row)
    __shared__ u16 Vt[2][64 * 64];   // 8 KB each: [d][kv pairs], see vt_write

    const int qb = 15 - (blockIdx.x >> 5);   // big tiles first
    const int bh = blockIdx.x & 31;
    const int b = bh >> 4, h = bh & 15;
    const int tid = threadIdx.x;
    const int w = tid >> 6, lane = tid & 63;
    const int g = lane >> 4, c = lane & 15;
    const int q0 = qb * 128;
    const u16* base = qkvh + (size_t)b * NN * QC;
    const int nrow = q0 + w * 16 + c;        // this lane's q row

    // staging indices: thread (srow, sch) stages K/V row srow, 8-dim chunk sch.
    // K source pre-swizzled so LDS chunk sch holds linear chunk sch^f(srow),
    // f(r) = (r&3)|(((r>>3)&1)<<2)  (equals c&7 on every read row).
    const int srow = tid >> 3, sch = tid & 7;
    const int kscol = (sch ^ ((srow & 3) | (((srow >> 3) & 1) << 2))) * 8;
    const u16* ksrc0 = base + (size_t)srow * QC + 1024 + h * 64 + kscol;
    const u16* vsrc0 = base + (size_t)srow * QC + 2048 + h * 64 + sch * 8;
    uint4 vreg;

    // ---- prologue: stage tile 0
    gload16(ksrc0, (char*)&Kb[0][0] + w * 1024);
    vreg = *(const uint4*)vsrc0;

    // ---- Q (roped in-register) + HK frags, qhk
    s16x8 qf[2], hf[2];
    float qh;
    {
        const u16* qp = base + (size_t)nrow * QC + h * 64;
        float accq = 0.f;
#pragma unroll
        for (int kk = 0; kk < 2; ++kk) {
            uint4 qv = *(const uint4*)(qp + ((kk * 4 + g) * 8));
            uint4 hv = *(const uint4*)(qp + 3072 + ((kk * 4 + g) * 8));
            const u16* qe = (const u16*)&qv;
            const u16* he = (const u16*)&hv;
            u32 ow[4];
#pragma unroll
            for (int m = 0; m < 4; ++m) {
                int i = (kk * 4 + g) * 4 + m;
                float co = tab[(nrow << 6) + i], si = tab[(nrow << 6) + 32 + i];
                float x0 = bf2f(qe[2 * m]), x1 = bf2f(qe[2 * m + 1]);
                float r0 = x0 * co - x1 * si;
                float r1 = x1 * co + x0 * si;
                accq += r0 * bf2f(he[2 * m]) + r1 * bf2f(he[2 * m + 1]);
                ow[m] = (u32)f2bf(r0) | ((u32)f2bf(r1) << 16);
            }
            union { s16x8 v; u32 u[4]; } uq, uh;
            uq.u[0] = ow[0]; uq.u[1] = ow[1]; uq.u[2] = ow[2]; uq.u[3] = ow[3];
            uh.u[0] = hv.x; uh.u[1] = hv.y; uh.u[2] = hv.z; uh.u[3] = hv.w;
            qf[kk] = uq.v; hf[kk] = uh.v;
        }
        accq += __shfl_xor(accq, 16);
        accq += __shfl_xor(accq, 32);
        qh = accq * SCALE;
    }
    const float sig_a = 1.f / (1.f + __expf(-alpha[h]));

    vt_write((char*)&Vt[0][0], vreg, srow, sch);
    __syncthreads();

    // ---- state
    f32x4 y[4];
#pragma unroll
    for (int db = 0; db < 4; ++db) { y[db][0] = 0.f; y[db][1] = 0.f; y[db][2] = 0.f; y[db][3] = 0.f; }
    float m = -INFINITY, l = 0.f;

    const int qmaxw = q0 + w * 16 + 15;
    const int KT = 2 * qb + 2;
    const int cbase = (8 * (c >> 2) + (c & 3)) * 128;   // permuted A-row base (bytes)

    for (int kt = 0; kt < KT; ++kt) {
        const int cur = kt & 1;
        const bool haveNext = (kt + 1 < KT);
        if (haveNext) {
            gload16(ksrc0 + (size_t)((kt + 1) * 64) * QC, (char*)&Kb[cur ^ 1][0] + w * 1024);
            vreg = *(const uint4*)(vsrc0 + (size_t)((kt + 1) * 64) * QC);
        }

        if (kt * 64 <= qmaxw) {
            // ---- S^T = K.Q^T and HKK^T (swapped, permuted K rows)
            f32x4 sq[4], sh4[4];
#pragma unroll
            for (int kb = 0; kb < 4; ++kb) {
                sq[kb][0] = 0.f; sq[kb][1] = 0.f; sq[kb][2] = 0.f; sq[kb][3] = 0.f;
                sh4[kb][0] = 0.f; sh4[kb][1] = 0.f; sh4[kb][2] = 0.f; sh4[kb][3] = 0.f;
            }
            const char* kbp = (const char*)&Kb[cur][0] + cbase;
#pragma unroll
            for (int kb = 0; kb < 4; ++kb) {
#pragma unroll
                for (int kk = 0; kk < 2; ++kk) {
                    s16x8 kf = *(const s16x8*)(kbp + (kb & 1) * 512 + (kb >> 1) * 4096 +
                                               ((((kk << 2) + g) ^ (c & 7)) << 4));
                    sq[kb] = __builtin_amdgcn_mfma_f32_16x16x32_bf16(kf, qf[kk], sq[kb], 0, 0, 0);
                    sh4[kb] = __builtin_amdgcn_mfma_f32_16x16x32_bf16(kf, hf[kk], sh4[kb], 0, 0, 0);
                }
            }
            // ---- scores + mask + online softmax (q = lane's own row)
            const bool needmask = (kt * 64 + 63 > q0 + w * 16);
            float mx = -INFINITY;
#pragma unroll
            for (int kb = 0; kb < 4; ++kb) {
#pragma unroll
                for (int e = 0; e < 4; ++e) {
                    float z = sh4[kb][e] * qh;
                    float sil = z / (1.f + __expf(-z));
                    float s = sq[kb][e] * SCALE - sil;
                    if (needmask) {
                        int kg = kt * 64 + 32 * (kb >> 1) + 8 * g + 4 * (kb & 1) + e;
                        if (kg > nrow) s = -INFINITY;
                    }
                    sq[kb][e] = s;
                    mx = fmaxf(mx, s);
                }
            }
            mx = fmaxf(mx, __shfl_xor(mx, 16));
            mx = fmaxf(mx, __shfl_xor(mx, 32));
            const float mnew = fmaxf(m, mx);
            const float scl = __expf(m - mnew);
            m = mnew;
            float rs = 0.f;
#pragma unroll
            for (int kb = 0; kb < 4; ++kb)
#pragma unroll
                for (int e = 0; e < 4; ++e) {
                    float p = __expf(sq[kb][e] - mnew);
                    sq[kb][e] = p;
                    rs += p;
                }
            rs += __shfl_xor(rs, 16);
            rs += __shfl_xor(rs, 32);
            l = l * scl + rs;
#pragma unroll
            for (int db = 0; db < 4; ++db) {
                y[db][0] *= scl; y[db][1] *= scl; y[db][2] *= scl; y[db][3] *= scl;
            }
            // ---- pack P into PV B-frag layout (zero-shuffle): j = e + 4*(kb&1)
            union { s16x8 v; u32 u[4]; } pa[2];
#pragma unroll
            for (int kk = 0; kk < 2; ++kk) {
                pa[kk].u[0] = cvtpk(sq[2 * kk][0], sq[2 * kk][1]);
                pa[kk].u[1] = cvtpk(sq[2 * kk][2], sq[2 * kk][3]);
                pa[kk].u[2] = cvtpk(sq[2 * kk + 1][0], sq[2 * kk + 1][1]);
                pa[kk].u[3] = cvtpk(sq[2 * kk + 1][2], sq[2 * kk + 1][3]);
            }
            // ---- y^T += V^T . P^T
            const char* vbp = (const char*)&Vt[cur][0];
#pragma unroll
            for (int kk = 0; kk < 2; ++kk)
#pragma unroll
                for (int db = 0; db < 4; ++db) {
                    int row = db * 16 + c;
                    s16x8 vfr = *(const s16x8*)(vbp + row * 128 + ((((kk << 2) + g) ^ (c & 7)) << 4));
                    y[db] = __builtin_amdgcn_mfma_f32_16x16x32_bf16(vfr, pa[kk].v, y[db], 0, 0, 0);
                }
        }

        if (haveNext) vt_write((char*)&Vt[cur ^ 1][0], vreg, srow, sch);
        __syncthreads();
    }

    // ---- epilogue: normalize, lookahead correction, store bf16
    const float inv_l = 1.f / l;
    const u16* hvp = base + (size_t)nrow * QC + 4096 + h * 64 + g * 4;
    float hv[4][4];
    float sdot = 0.f;
#pragma unroll
    for (int db = 0; db < 4; ++db) {
        uint2 hw = *(const uint2*)(hvp + db * 16);
        const u16* he = (const u16*)&hw;
#pragma unroll
        for (int e = 0; e < 4; ++e) {
            hv[db][e] = bf2f(he[e]);
            float yn = y[db][e] * inv_l;
            y[db][e] = yn;
            sdot += yn * hv[db][e];
        }
    }
    sdot += __shfl_xor(sdot, 16);
    sdot += __shfl_xor(sdot, 32);
    const float f = sig_a * sdot;
    u16* op = aout + ((size_t)(b * NN + nrow)) * DD + h * 64 + g * 4;
#pragma unroll
    for (int db = 0; db < 4; ++db) {
        u32 o0 = (u32)f2bf(y[db][0] - f * hv[db][0]) | ((u32)f2bf(y[db][1] - f * hv[db][1]) << 16);
        u32 o1 = (u32)f2bf(y[db][2] - f * hv[db][2]) | ((u32)f2bf(y[db][3] - f * hv[db][3]) << 16);
        *(uint2*)(op + db * 16) = make_uint2(o0, o1);
    }
}

// ---------------------------------------------------------------------------
extern "C" void kernel_launch(void* const* d_in, const int* in_sizes, int n_in,
                              void* d_out, int out_size, void* d_ws, size_t ws_size,
                              hipStream_t stream)
{
    const float* x     = (const float*)d_in[0];
    const float* w_qkv = (const float*)d_in[1];
    const float* w_hkv = (const float*)d_in[2];
    const float* w_out = (const float*)d_in[3];
    const float* b_out = (const float*)d_in[4];
    const float* alpha = (const float*)d_in[5];

    char* ws = (char*)d_ws;
    u16*   qkvh = (u16*)ws;                       // 4096x5120 bf16
    uint4* xb   = (uint4*)(ws + 41943040);        // 4096x1024 bf16
    u16*   wT   = (u16*)(ws + 50331648);          // 6144x1024 bf16
    u16*   aout = (u16*)(ws + 62914560);          // 4096x1024 bf16
    float* tab  = (float*)(ws + 71303168);        // 2048x64 f32

    convert_x<<<2048, 256, 0, stream>>>(x, xb);
    transpose_w<<<dim3(96, 16), 256, 0, stream>>>(w_qkv, w_hkv, w_out, wT);
    rope_table<<<512, 256, 0, stream>>>(tab);

    // 1) qkvh = x @ [w_qkv | w_hkv]
    gemm_bf16<1><<<dim3(40, 32), 256, 0, stream>>>(
        (const u16*)xb, 1024, wT, 1024, qkvh, QC, nullptr, 1024);

    // 2) RoPE on K region only (Q roped inside attn)
    rope_k<<<8192, 256, 0, stream>>>(qkvh, tab);

    // 3) fused attention -> aout
    attn<<<512, 512, 0, stream>>>(qkvh, alpha, tab, aout);

    // 4) out = aout @ w_out + b_out
    gemm_bf16<0><<<dim3(8, 32), 256, 0, stream>>>(
        aout, 1024, wT + 5120 * 1024, 1024, d_out, 1024, b_out, 1024);
}

// Round 5
// 183.836 us; speedup vs baseline: 18.4143x; 1.1535x over previous
//
#include <hip/hip_runtime.h>
#include <math.h>

typedef unsigned int u32;
typedef unsigned short u16;
typedef __attribute__((ext_vector_type(4))) float f32x4;
typedef __attribute__((ext_vector_type(8))) short s16x8;   // 8 bf16 (MFMA A/B frag)

#define BB 2
#define NN 2048
#define DD 1024
#define HH 16
#define ROWS 4096
#define QC 5120            // qkvh cols: q|k|v|hk|hv
#define SCALE 0.125f
#define LOG2E 1.44269504088896f
#define SC2 (SCALE * LOG2E)

#if __has_builtin(__builtin_amdgcn_exp2f)
#define EXP2(x) __builtin_amdgcn_exp2f(x)
#else
#define EXP2(x) __expf((x) * 0.69314718056f)
#endif
#if __has_builtin(__builtin_amdgcn_rcpf)
#define RCP(x) __builtin_amdgcn_rcpf(x)
#else
#define RCP(x) (1.0f / (x))
#endif

__device__ __forceinline__ u16 f2bf(float x) {
    u32 u = __float_as_uint(x);
    return (u16)((u + 0x7FFFu + ((u >> 16) & 1u)) >> 16);
}
__device__ __forceinline__ float bf2f(u16 h) {
    return __uint_as_float(((u32)h) << 16);
}
__device__ __forceinline__ u32 cvtpk(float lo, float hi) {
    u32 r;
    asm("v_cvt_pk_bf16_f32 %0, %1, %2" : "=v"(r) : "v"(lo), "v"(hi));
    return r;
}
__device__ __forceinline__ void gload16(const void* g, void* l) {
    __builtin_amdgcn_global_load_lds(
        (const __attribute__((address_space(1))) unsigned int*)g,
        (__attribute__((address_space(3))) unsigned int*)l, 16, 0, 0);
}

// Transpose a 64x64 V tile into Vt[d][kv] (bf16-pair packed, XOR-swizzled
// chunks). Thread holds V[srow][sch*8..+7] in vreg; partner (srow^1 = tid^8,
// same sch) supplies the adjacent kv row. Even srow writes dims sch*8..+3,
// odd writes sch*8+4..+7, for kv pair (2s,2s+1), s = srow>>1. Slot:
// d*128 + ((s>>2)^(d&7))*16 + (s&3)*4  — bijective.
__device__ __forceinline__ void vt_write(char* vbb, uint4 vreg, int srow, int sch)
{
    uint4 oth;
    oth.x = (u32)__shfl_xor((int)vreg.x, 8); oth.y = (u32)__shfl_xor((int)vreg.y, 8);
    oth.z = (u32)__shfl_xor((int)vreg.z, 8); oth.w = (u32)__shfl_xor((int)vreg.w, 8);
    const bool odd = (srow & 1);
    u32 ma = odd ? vreg.z : vreg.x, mb = odd ? vreg.w : vreg.y;
    u32 oa = odd ? oth.z : oth.x,  ob = odd ? oth.w : oth.y;
    u32 ea = odd ? oa : ma, eb = odd ? ob : mb;   // even kv row (2s)
    u32 da = odd ? ma : oa, db = odd ? mb : ob;   // odd  kv row (2s+1)
    u32 pk0 = (ea & 0xffffu) | (da << 16);
    u32 pk1 = (ea >> 16)     | (da & 0xffff0000u);
    u32 pk2 = (eb & 0xffffu) | (db << 16);
    u32 pk3 = (eb >> 16)     | (db & 0xffff0000u);
    const int s = srow >> 1;
    const int d0 = sch * 8 + (odd ? 4 : 0);
    *(u32*)(vbb + (d0 + 0) * 128 + ((((s >> 2) ^ ((d0 + 0) & 7)) << 4)) + (s & 3) * 4) = pk0;
    *(u32*)(vbb + (d0 + 1) * 128 + ((((s >> 2) ^ ((d0 + 1) & 7)) << 4)) + (s & 3) * 4) = pk1;
    *(u32*)(vbb + (d0 + 2) * 128 + ((((s >> 2) ^ ((d0 + 2) & 7)) << 4)) + (s & 3) * 4) = pk2;
    *(u32*)(vbb + (d0 + 3) * 128 + ((((s >> 2) ^ ((d0 + 3) & 7)) << 4)) + (s & 3) * 4) = pk3;
}

// ---------------------------------------------------------------------------
// Prep: x (f32) -> bf16
// ---------------------------------------------------------------------------
__global__ __launch_bounds__(256) void convert_x(const float* __restrict__ x,
                                                 uint4* __restrict__ xb)
{
    int t = blockIdx.x * 256 + threadIdx.x;
    const float4 a = ((const float4*)x)[2 * t];
    const float4 b = ((const float4*)x)[2 * t + 1];
    uint4 o;
    o.x = f2bf(a.x) | ((u32)f2bf(a.y) << 16);
    o.y = f2bf(a.z) | ((u32)f2bf(a.w) << 16);
    o.z = f2bf(b.x) | ((u32)f2bf(b.y) << 16);
    o.w = f2bf(b.z) | ((u32)f2bf(b.w) << 16);
    xb[t] = o;
}

// ---------------------------------------------------------------------------
// Prep: weights -> wT[c][k] bf16 (rows 0..5119 = [wqkv|whkv], 5120.. = w_out^T)
// ---------------------------------------------------------------------------
__global__ __launch_bounds__(256) void transpose_w(const float* __restrict__ wqkv,
                                                   const float* __restrict__ whkv,
                                                   const float* __restrict__ wout,
                                                   u16* __restrict__ wT)
{
    __shared__ float T[64][65];
    const int bc = blockIdx.x;
    const int k0 = blockIdx.y * 64;
    const int c0 = bc * 64;
    const float* src; int stride; int csrc;
    if (bc < 48)      { src = wqkv; stride = 3072; csrc = c0; }
    else if (bc < 80) { src = whkv; stride = 2048; csrc = c0 - 3072; }
    else              { src = wout; stride = 1024; csrc = c0 - 5120; }
    const int t = threadIdx.x;
    const int r = t >> 4, c4 = t & 15;
#pragma unroll
    for (int i = 0; i < 4; ++i) {
        int kk = r + 16 * i;
        float4 v = *(const float4*)&src[(size_t)(k0 + kk) * stride + csrc + 4 * c4];
        T[kk][4 * c4 + 0] = v.x; T[kk][4 * c4 + 1] = v.y;
        T[kk][4 * c4 + 2] = v.z; T[kk][4 * c4 + 3] = v.w;
    }
    __syncthreads();
#pragma unroll
    for (int i = 0; i < 4; ++i) {
        int cc = r + 16 * i;
        u32 lo = f2bf(T[4 * c4 + 0][cc]) | ((u32)f2bf(T[4 * c4 + 1][cc]) << 16);
        u32 hi = f2bf(T[4 * c4 + 2][cc]) | ((u32)f2bf(T[4 * c4 + 3][cc]) << 16);
        *(uint2*)&wT[(size_t)(c0 + cc) * 1024 + k0 + 4 * c4] = make_uint2(lo, hi);
    }
}

// ---------------------------------------------------------------------------
// Prep: rope table  tab[n][0..31]=cos, tab[n][32..63]=sin
// ---------------------------------------------------------------------------
__global__ __launch_bounds__(256) void rope_table(float* __restrict__ tab)
{
    int t = blockIdx.x * 256 + threadIdx.x;
    int n = t >> 6, col = t & 63, i = col & 31;
    float ang = (float)n * exp2f(-(float)i * 0.41524101186092029f);
    tab[t] = (col < 32) ? cosf(ang) : sinf(ang);
}

// ---------------------------------------------------------------------------
// bf16 MFMA GEMM: C[M][N] = A[M][K] @ B^T (B = wT[N][K]); global_load_lds
// staging (pre-swizzled source, linear LDS dest). 128x128 tile, BK=64.
// BF16_OUT=1 also applies RoPE to the K region (cols 1024..2047) on fp32 acc.
// ---------------------------------------------------------------------------
template <int BF16_OUT>
__global__ __launch_bounds__(256, 2) void gemm_bf16(
    const u16* __restrict__ A, int lda,
    const u16* __restrict__ B, int ldb,
    void* __restrict__ C, int ldc,
    const float* __restrict__ bias, const float* __restrict__ tab, int K)
{
    __shared__ u16 As[128 * 64];   // 16KB, [row][64k] bf16; chunk cl at cl^(row&7)
    __shared__ u16 Bs[128 * 64];
    const int tid = threadIdx.x;
    const int lane = tid & 63, w = tid >> 6;
    const int g = lane >> 4, c = lane & 15;
    const int wr = w >> 1, wc = w & 1;
    const int rb0 = blockIdx.y * 128, cb0 = blockIdx.x * 128;

    f32x4 acc[4][4];
#pragma unroll
    for (int i = 0; i < 4; ++i)
#pragma unroll
        for (int j = 0; j < 4; ++j) {
            acc[i][j][0] = 0.f; acc[i][j][1] = 0.f; acc[i][j][2] = 0.f; acc[i][j][3] = 0.f;
        }

    const int srow = tid >> 3, sch = tid & 7;
    const int scol = ((sch ^ (srow & 7)) * 8);
    const u16* asrc = A + (size_t)(rb0 + srow) * lda + scol;
    const u16* bsrc = B + (size_t)(cb0 + srow) * ldb + scol;

    for (int k0 = 0; k0 < K; k0 += 64) {
        __syncthreads();
#pragma unroll
        for (int r = 0; r < 4; ++r) {
            gload16(asrc + (size_t)(32 * r) * lda + k0, (char*)As + r * 4096 + w * 1024);
            gload16(bsrc + (size_t)(32 * r) * ldb + k0, (char*)Bs + r * 4096 + w * 1024);
        }
        __syncthreads();
#pragma unroll
        for (int kk = 0; kk < 2; ++kk) {
            s16x8 a[4], b[4];
#pragma unroll
            for (int rb = 0; rb < 4; ++rb) {
                int row = wr * 64 + rb * 16 + c;
                a[rb] = *(const s16x8*)((const char*)As + row * 128 + ((((kk << 2) + g) ^ (row & 7)) << 4));
            }
#pragma unroll
            for (int cb = 0; cb < 4; ++cb) {
                int row = wc * 64 + cb * 16 + c;
                b[cb] = *(const s16x8*)((const char*)Bs + row * 128 + ((((kk << 2) + g) ^ (row & 7)) << 4));
            }
#pragma unroll
            for (int rb = 0; rb < 4; ++rb)
#pragma unroll
                for (int cb = 0; cb < 4; ++cb)
                    acc[rb][cb] = __builtin_amdgcn_mfma_f32_16x16x32_bf16(a[rb], b[cb], acc[rb][cb], 0, 0, 0);
        }
    }

    // ---- fused RoPE on K region (pairs = adjacent cols = adjacent lanes)
    if (BF16_OUT && tab && cb0 >= 1024 && cb0 < 2048) {
#pragma unroll
        for (int rb = 0; rb < 4; ++rb)
#pragma unroll
            for (int cb = 0; cb < 4; ++cb) {
                const int i = ((wc * 64 + cb * 16 + c) & 63) >> 1;
#pragma unroll
                for (int e = 0; e < 4; ++e) {
                    int n = (rb0 + wr * 64 + rb * 16 + g * 4 + e) & (NN - 1);
                    float co = tab[(n << 6) + i], si = tab[(n << 6) + 32 + i];
                    float self = acc[rb][cb][e];
                    float part = __shfl_xor(self, 1);
                    acc[rb][cb][e] = (c & 1) ? fmaf(self, co, part * si)
                                             : fmaf(self, co, -part * si);
                }
            }
    }

#pragma unroll
    for (int rb = 0; rb < 4; ++rb) {
#pragma unroll
        for (int cb = 0; cb < 4; ++cb) {
            if (BF16_OUT) {
                uint2 keep = make_uint2(0, 0);
#pragma unroll
                for (int e = 0; e < 4; ++e) {
                    u32 me = f2bf(acc[rb][cb][e]);
                    u32 x1 = (u32)__shfl_xor((int)me, 1);
                    u32 pair = (c & 1) ? ((x1 & 0xffffu) | (me << 16)) : ((me & 0xffffu) | (x1 << 16));
                    u32 x2 = (u32)__shfl_xor((int)pair, 2);
                    u32 q0 = (c & 2) ? x2 : pair;
                    u32 q1 = (c & 2) ? pair : x2;
                    if ((c & 3) == e) keep = make_uint2(q0, q1);
                }
                int row = rb0 + wr * 64 + rb * 16 + g * 4 + (c & 3);
                int col = cb0 + wc * 64 + cb * 16 + (c & ~3);
                *(uint2*)((u16*)C + (size_t)row * ldc + col) = keep;
            } else {
                int col = cb0 + wc * 64 + cb * 16 + c;
                float bv = bias ? bias[col] : 0.f;
#pragma unroll
                for (int e = 0; e < 4; ++e) {
                    int row = rb0 + wr * 64 + rb * 16 + g * 4 + e;
                    ((float*)C)[(size_t)row * ldc + col] = acc[rb][cb][e] + bv;
                }
            }
        }
    }
}

// ---------------------------------------------------------------------------
// Fused lookahead attention, swapped-layout (lane owns q-row = lane&15).
// Block = (b,h, paired 64-row q tiles qt & 31-qt): constant 33 kv tiles per
// block -> no causal tail imbalance. 4 waves x 16 rows, kv tiles of 64,
// dbuf K/V^T. K frag rows permuted so softmax'd P lands directly in the PV
// B-fragment layout (zero-shuffle P). Softmax in exp2 domain, rcp-based silu.
// ---------------------------------------------------------------------------
__global__ __launch_bounds__(256, 4) void attn(
    const u16* __restrict__ qkvh, const float* __restrict__ alpha,
    const float* __restrict__ tab, u16* __restrict__ aout)
{
    __shared__ u16 Kb[2][64 * 64];   // 8 KB each
    __shared__ u16 Vt[2][64 * 64];   // 8 KB each

    const int bid = blockIdx.x;
    const int swz = (bid & 7) * 64 + (bid >> 3);   // XCD-contiguous, bijective
    const int bh = swz >> 4;                        // 0..31
    const int qp = swz & 15;                        // pair id
    const int b = bh >> 4, h = bh & 15;
    const int tid = threadIdx.x;
    const int w = tid >> 6, lane = tid & 63;
    const int g = lane >> 4, c = lane & 15;
    const u16* base = qkvh + (size_t)b * NN * QC;

    // staging indices (srow in [0,32); also covers srow+32)
    const int srow = tid >> 3, sch = tid & 7;
    const int kscol = (sch ^ ((srow & 3) | (((srow >> 3) & 1) << 2))) * 8;
    const u16* ksrc0 = base + (size_t)srow * QC + 1024 + h * 64 + kscol;
    const u16* vsrc0 = base + (size_t)srow * QC + 2048 + h * 64 + sch * 8;

    const float sig_a = RCP(1.f + EXP2(-alpha[h] * LOG2E));
    const int cbase = (8 * (c >> 2) + (c & 3)) * 128;   // permuted A-row base

#pragma unroll 1
    for (int ph = 0; ph < 2; ++ph) {
        const int qt = ph ? (31 - qp) : qp;
        const int q0 = qt * 64;
        const int nrow = q0 + w * 16 + c;

        // ---- stage kv tile 0
        gload16(ksrc0 + (size_t)(q0 - q0) , (char*)&Kb[0][0] + w * 1024);  // tile 0 rows 0..31
        gload16(ksrc0 + (size_t)32 * QC, (char*)&Kb[0][0] + 4096 + w * 1024);
        uint4 vr0 = *(const uint4*)vsrc0;
        uint4 vr1 = *(const uint4*)(vsrc0 + (size_t)32 * QC);
        vt_write((char*)&Vt[0][0], vr0, srow, sch);
        vt_write((char*)&Vt[0][0], vr1, srow + 32, sch);

        // ---- Q (roped in-register) + HK frags, qhk (log2e-scaled)
        s16x8 qf[2], hf[2];
        float qhL;
        {
            const u16* qp_ = base + (size_t)nrow * QC + h * 64;
            float accq = 0.f;
#pragma unroll
            for (int kk = 0; kk < 2; ++kk) {
                uint4 qv = *(const uint4*)(qp_ + ((kk * 4 + g) * 8));
                uint4 hv = *(const uint4*)(qp_ + 3072 + ((kk * 4 + g) * 8));
                const u16* qe = (const u16*)&qv;
                const u16* he = (const u16*)&hv;
                u32 ow[4];
#pragma unroll
                for (int m2 = 0; m2 < 4; ++m2) {
                    int i = (kk * 4 + g) * 4 + m2;
                    float co = tab[(nrow << 6) + i], si = tab[(nrow << 6) + 32 + i];
                    float x0 = bf2f(qe[2 * m2]), x1 = bf2f(qe[2 * m2 + 1]);
                    float r0 = x0 * co - x1 * si;
                    float r1 = x1 * co + x0 * si;
                    accq += r0 * bf2f(he[2 * m2]) + r1 * bf2f(he[2 * m2 + 1]);
                    ow[m2] = (u32)f2bf(r0) | ((u32)f2bf(r1) << 16);
                }
                union { s16x8 v; u32 u[4]; } uq, uh;
                uq.u[0] = ow[0]; uq.u[1] = ow[1]; uq.u[2] = ow[2]; uq.u[3] = ow[3];
                uh.u[0] = hv.x; uh.u[1] = hv.y; uh.u[2] = hv.z; uh.u[3] = hv.w;
                qf[kk] = uq.v; hf[kk] = uh.v;
            }
            accq += __shfl_xor(accq, 16);
            accq += __shfl_xor(accq, 32);
            qhL = accq * SC2;
        }
        __syncthreads();

        // ---- state
        f32x4 y[4];
#pragma unroll
        for (int db = 0; db < 4; ++db) { y[db][0] = 0.f; y[db][1] = 0.f; y[db][2] = 0.f; y[db][3] = 0.f; }
        float m = -INFINITY, l = 0.f;

        for (int kt = 0; kt <= qt; ++kt) {
            const int cur = kt & 1;
            const bool haveNext = (kt < qt);
            uint4 vr0n, vr1n;
            if (haveNext) {
                gload16(ksrc0 + (size_t)((kt + 1) * 64) * QC, (char*)&Kb[cur ^ 1][0] + w * 1024);
                gload16(ksrc0 + (size_t)((kt + 1) * 64 + 32) * QC, (char*)&Kb[cur ^ 1][0] + 4096 + w * 1024);
                vr0n = *(const uint4*)(vsrc0 + (size_t)((kt + 1) * 64) * QC);
                vr1n = *(const uint4*)(vsrc0 + (size_t)((kt + 1) * 64 + 32) * QC);
            }

            // ---- S^T = K.Q^T and HKK^T (swapped, permuted K rows)
            f32x4 sq[4], sh4[4];
#pragma unroll
            for (int kb = 0; kb < 4; ++kb) {
                sq[kb][0] = 0.f; sq[kb][1] = 0.f; sq[kb][2] = 0.f; sq[kb][3] = 0.f;
                sh4[kb][0] = 0.f; sh4[kb][1] = 0.f; sh4[kb][2] = 0.f; sh4[kb][3] = 0.f;
            }
            const char* kbp = (const char*)&Kb[cur][0] + cbase;
#pragma unroll
            for (int kb = 0; kb < 4; ++kb) {
#pragma unroll
                for (int kk = 0; kk < 2; ++kk) {
                    s16x8 kf = *(const s16x8*)(kbp + (kb & 1) * 512 + (kb >> 1) * 4096 +
                                               ((((kk << 2) + g) ^ (c & 7)) << 4));
                    sq[kb] = __builtin_amdgcn_mfma_f32_16x16x32_bf16(kf, qf[kk], sq[kb], 0, 0, 0);
                    sh4[kb] = __builtin_amdgcn_mfma_f32_16x16x32_bf16(kf, hf[kk], sh4[kb], 0, 0, 0);
                }
            }
            // ---- scores (exp2 domain) + mask + online softmax
            const bool needmask = (kt == qt);
            float mx = -INFINITY;
#pragma unroll
            for (int kb = 0; kb < 4; ++kb) {
#pragma unroll
                for (int e = 0; e < 4; ++e) {
                    float zp = sh4[kb][e] * qhL;                     // z*log2e
                    float sil = zp * RCP(1.f + EXP2(-zp));           // silu(z)*log2e
                    float s = fmaf(sq[kb][e], SC2, -sil);            // score*log2e
                    if (needmask) {
                        int kg = kt * 64 + 32 * (kb >> 1) + 8 * g + 4 * (kb & 1) + e;
                        if (kg > nrow) s = -INFINITY;
                    }
                    sq[kb][e] = s;
                    mx = fmaxf(mx, s);
                }
            }
            mx = fmaxf(mx, __shfl_xor(mx, 16));
            mx = fmaxf(mx, __shfl_xor(mx, 32));
            const float mnew = fmaxf(m, mx);
            const float scl = EXP2(m - mnew);
            m = mnew;
            float rs = 0.f;
#pragma unroll
            for (int kb = 0; kb < 4; ++kb)
#pragma unroll
                for (int e = 0; e < 4; ++e) {
                    float p = EXP2(sq[kb][e] - mnew);
                    sq[kb][e] = p;
                    rs += p;
                }
            rs += __shfl_xor(rs, 16);
            rs += __shfl_xor(rs, 32);
            l = l * scl + rs;
#pragma unroll
            for (int db = 0; db < 4; ++db) {
                y[db][0] *= scl; y[db][1] *= scl; y[db][2] *= scl; y[db][3] *= scl;
            }
            // ---- pack P into PV B-frag layout (zero-shuffle): j = e + 4*(kb&1)
            union { s16x8 v; u32 u[4]; } pa[2];
#pragma unroll
            for (int kk = 0; kk < 2; ++kk) {
                pa[kk].u[0] = cvtpk(sq[2 * kk][0], sq[2 * kk][1]);
                pa[kk].u[1] = cvtpk(sq[2 * kk][2], sq[2 * kk][3]);
                pa[kk].u[2] = cvtpk(sq[2 * kk + 1][0], sq[2 * kk + 1][1]);
                pa[kk].u[3] = cvtpk(sq[2 * kk + 1][2], sq[2 * kk + 1][3]);
            }
            // ---- y^T += V^T . P^T
            const char* vbp = (const char*)&Vt[cur][0];
#pragma unroll
            for (int kk = 0; kk < 2; ++kk)
#pragma unroll
                for (int db = 0; db < 4; ++db) {
                    int row = db * 16 + c;
                    s16x8 vfr = *(const s16x8*)(vbp + row * 128 + ((((kk << 2) + g) ^ (c & 7)) << 4));
                    y[db] = __builtin_amdgcn_mfma_f32_16x16x32_bf16(vfr, pa[kk].v, y[db], 0, 0, 0);
                }

            if (haveNext) {
                vt_write((char*)&Vt[cur ^ 1][0], vr0n, srow, sch);
                vt_write((char*)&Vt[cur ^ 1][0], vr1n, srow + 32, sch);
            }
            __syncthreads();
        }

        // ---- epilogue: normalize, lookahead correction, store bf16
        const float inv_l = RCP(l);
        const u16* hvp = base + (size_t)nrow * QC + 4096 + h * 64 + g * 4;
        float hv[4][4];
        float sdot = 0.f;
#pragma unroll
        for (int db = 0; db < 4; ++db) {
            uint2 hw = *(const uint2*)(hvp + db * 16);
            const u16* he = (const u16*)&hw;
#pragma unroll
            for (int e = 0; e < 4; ++e) {
                hv[db][e] = bf2f(he[e]);
                float yn = y[db][e] * inv_l;
                y[db][e] = yn;
                sdot += yn * hv[db][e];
            }
        }
        sdot += __shfl_xor(sdot, 1); sdot += __shfl_xor(sdot, 2);
        sdot += __shfl_xor(sdot, 4); sdot += __shfl_xor(sdot, 8);
        // NOTE: y layout here: lane owns q-row (c), dims split g*4+e over 16
        // lanes sharing c — the hv.y dot needs reduction over dims = over g
        // groups and e. e is in-register (summed above), g via xor 16/32.
        // (the xor 1/2/4/8 above was WRONG domain — corrected below)
        sdot = 0.f;
#pragma unroll
        for (int db = 0; db < 4; ++db)
#pragma unroll
            for (int e = 0; e < 4; ++e) sdot += y[db][e] * hv[db][e];
        sdot += __shfl_xor(sdot, 16);
        sdot += __shfl_xor(sdot, 32);
        const float f = sig_a * sdot;
        u16* op = aout + ((size_t)(b * NN + nrow)) * DD + h * 64 + g * 4;
#pragma unroll
        for (int db = 0; db < 4; ++db) {
            u32 o0 = (u32)f2bf(y[db][0] - f * hv[db][0]) | ((u32)f2bf(y[db][1] - f * hv[db][1]) << 16);
            u32 o1 = (u32)f2bf(y[db][2] - f * hv[db][2]) | ((u32)f2bf(y[db][3] - f * hv[db][3]) << 16);
            *(uint2*)(op + db * 16) = make_uint2(o0, o1);
        }
        __syncthreads();   // phase boundary: all compute done before restaging
    }
}

// ---------------------------------------------------------------------------
extern "C" void kernel_launch(void* const* d_in, const int* in_sizes, int n_in,
                              void* d_out, int out_size, void* d_ws, size_t ws_size,
                              hipStream_t stream)
{
    const float* x     = (const float*)d_in[0];
    const float* w_qkv = (const float*)d_in[1];
    const float* w_hkv = (const float*)d_in[2];
    const float* w_out = (const float*)d_in[3];
    const float* b_out = (const float*)d_in[4];
    const float* alpha = (const float*)d_in[5];

    char* ws = (char*)d_ws;
    u16*   qkvh = (u16*)ws;                       // 4096x5120 bf16
    uint4* xb   = (uint4*)(ws + 41943040);        // 4096x1024 bf16
    u16*   wT   = (u16*)(ws + 50331648);          // 6144x1024 bf16
    u16*   aout = (u16*)(ws + 62914560);          // 4096x1024 bf16
    float* tab  = (float*)(ws + 71303168);        // 2048x64 f32

    convert_x<<<2048, 256, 0, stream>>>(x, xb);
    transpose_w<<<dim3(96, 16), 256, 0, stream>>>(w_qkv, w_hkv, w_out, wT);
    rope_table<<<512, 256, 0, stream>>>(tab);

    // 1) qkvh = x @ [w_qkv | w_hkv]  (+ fused K-RoPE in epilogue)
    gemm_bf16<1><<<dim3(40, 32), 256, 0, stream>>>(
        (const u16*)xb, 1024, wT, 1024, qkvh, QC, nullptr, tab, 1024);

    // 2) fused attention -> aout  (Q roped in-register inside)
    attn<<<512, 256, 0, stream>>>(qkvh, alpha, tab, aout);

    // 3) out = aout @ w_out + b_out
    gemm_bf16<0><<<dim3(8, 32), 256, 0, stream>>>(
        aout, 1024, wT + 5120 * 1024, 1024, d_out, 1024, b_out, nullptr, 1024);
}

// Round 6
// 168.463 us; speedup vs baseline: 20.0947x; 1.0913x over previous
//
#include <hip/hip_runtime.h>
#include <math.h>

typedef unsigned int u32;
typedef unsigned short u16;
typedef __attribute__((ext_vector_type(4))) float f32x4;
typedef __attribute__((ext_vector_type(8))) short s16x8;   // 8 bf16 (MFMA A/B frag)

#define BB 2
#define NN 2048
#define DD 1024
#define HH 16
#define ROWS 4096
#define QC 5120            // qkvh cols: q|k|v|hk|hv
#define SCALE 0.125f
#define LOG2E 1.44269504088896f
#define SC2 (SCALE * LOG2E)

#if __has_builtin(__builtin_amdgcn_exp2f)
#define EXP2(x) __builtin_amdgcn_exp2f(x)
#else
#define EXP2(x) __expf((x) * 0.69314718056f)
#endif
#if __has_builtin(__builtin_amdgcn_rcpf)
#define RCP(x) __builtin_amdgcn_rcpf(x)
#else
#define RCP(x) (1.0f / (x))
#endif

__device__ __forceinline__ u16 f2bf(float x) {
    u32 u = __float_as_uint(x);
    return (u16)((u + 0x7FFFu + ((u >> 16) & 1u)) >> 16);
}
__device__ __forceinline__ float bf2f(u16 h) {
    return __uint_as_float(((u32)h) << 16);
}
__device__ __forceinline__ u32 cvtpk(float lo, float hi) {
    u32 r;
    asm("v_cvt_pk_bf16_f32 %0, %1, %2" : "=v"(r) : "v"(lo), "v"(hi));
    return r;
}
__device__ __forceinline__ void gload16(const void* g, void* l) {
    __builtin_amdgcn_global_load_lds(
        (const __attribute__((address_space(1))) unsigned int*)g,
        (__attribute__((address_space(3))) unsigned int*)l, 16, 0, 0);
}

// Transpose a 64x64 V tile into Vt[d][kv] (bf16-pair packed, XOR-swizzled
// chunks). Thread holds V[srow][sch*8..+7] in vreg; partner (srow^1 = tid^8,
// same sch) supplies the adjacent kv row. Even srow writes dims sch*8..+3,
// odd writes sch*8+4..+7, for kv pair (2s,2s+1), s = srow>>1. Slot:
// d*128 + ((s>>2)^(d&7)^(d>>3))*16 + (s&3)*4  — bijective, and the ^(d>>3)
// (= sch) term spreads a wave's stores across all 32 banks (2 lanes/bank;
// without it 8 lanes/bank on 8 banks = the r5 7.57M conflict counter).
__device__ __forceinline__ void vt_write(char* vbb, uint4 vreg, int srow, int sch)
{
    uint4 oth;
    oth.x = (u32)__shfl_xor((int)vreg.x, 8); oth.y = (u32)__shfl_xor((int)vreg.y, 8);
    oth.z = (u32)__shfl_xor((int)vreg.z, 8); oth.w = (u32)__shfl_xor((int)vreg.w, 8);
    const bool odd = (srow & 1);
    u32 ma = odd ? vreg.z : vreg.x, mb = odd ? vreg.w : vreg.y;
    u32 oa = odd ? oth.z : oth.x,  ob = odd ? oth.w : oth.y;
    u32 ea = odd ? oa : ma, eb = odd ? ob : mb;   // even kv row (2s)
    u32 da = odd ? ma : oa, db = odd ? mb : ob;   // odd  kv row (2s+1)
    u32 pk0 = (ea & 0xffffu) | (da << 16);
    u32 pk1 = (ea >> 16)     | (da & 0xffff0000u);
    u32 pk2 = (eb & 0xffffu) | (db << 16);
    u32 pk3 = (eb >> 16)     | (db & 0xffff0000u);
    const int s = srow >> 1;
    const int d0 = sch * 8 + (odd ? 4 : 0);
    const int sb = (s & 3) * 4;
    *(u32*)(vbb + (d0 + 0) * 128 + ((((s >> 2) ^ ((d0 + 0) & 7) ^ sch) << 4)) + sb) = pk0;
    *(u32*)(vbb + (d0 + 1) * 128 + ((((s >> 2) ^ ((d0 + 1) & 7) ^ sch) << 4)) + sb) = pk1;
    *(u32*)(vbb + (d0 + 2) * 128 + ((((s >> 2) ^ ((d0 + 2) & 7) ^ sch) << 4)) + sb) = pk2;
    *(u32*)(vbb + (d0 + 3) * 128 + ((((s >> 2) ^ ((d0 + 3) & 7) ^ sch) << 4)) + sb) = pk3;
}

// ---------------------------------------------------------------------------
// Prep: x (f32) -> bf16
// ---------------------------------------------------------------------------
__global__ __launch_bounds__(256) void convert_x(const float* __restrict__ x,
                                                 uint4* __restrict__ xb)
{
    int t = blockIdx.x * 256 + threadIdx.x;
    const float4 a = ((const float4*)x)[2 * t];
    const float4 b = ((const float4*)x)[2 * t + 1];
    uint4 o;
    o.x = f2bf(a.x) | ((u32)f2bf(a.y) << 16);
    o.y = f2bf(a.z) | ((u32)f2bf(a.w) << 16);
    o.z = f2bf(b.x) | ((u32)f2bf(b.y) << 16);
    o.w = f2bf(b.z) | ((u32)f2bf(b.w) << 16);
    xb[t] = o;
}

// ---------------------------------------------------------------------------
// Prep: weights -> wT[c][k] bf16 (rows 0..5119 = [wqkv|whkv], 5120.. = w_out^T)
// ---------------------------------------------------------------------------
__global__ __launch_bounds__(256) void transpose_w(const float* __restrict__ wqkv,
                                                   const float* __restrict__ whkv,
                                                   const float* __restrict__ wout,
                                                   u16* __restrict__ wT)
{
    __shared__ float T[64][65];
    const int bc = blockIdx.x;
    const int k0 = blockIdx.y * 64;
    const int c0 = bc * 64;
    const float* src; int stride; int csrc;
    if (bc < 48)      { src = wqkv; stride = 3072; csrc = c0; }
    else if (bc < 80) { src = whkv; stride = 2048; csrc = c0 - 3072; }
    else              { src = wout; stride = 1024; csrc = c0 - 5120; }
    const int t = threadIdx.x;
    const int r = t >> 4, c4 = t & 15;
#pragma unroll
    for (int i = 0; i < 4; ++i) {
        int kk = r + 16 * i;
        float4 v = *(const float4*)&src[(size_t)(k0 + kk) * stride + csrc + 4 * c4];
        T[kk][4 * c4 + 0] = v.x; T[kk][4 * c4 + 1] = v.y;
        T[kk][4 * c4 + 2] = v.z; T[kk][4 * c4 + 3] = v.w;
    }
    __syncthreads();
#pragma unroll
    for (int i = 0; i < 4; ++i) {
        int cc = r + 16 * i;
        u32 lo = f2bf(T[4 * c4 + 0][cc]) | ((u32)f2bf(T[4 * c4 + 1][cc]) << 16);
        u32 hi = f2bf(T[4 * c4 + 2][cc]) | ((u32)f2bf(T[4 * c4 + 3][cc]) << 16);
        *(uint2*)&wT[(size_t)(c0 + cc) * 1024 + k0 + 4 * c4] = make_uint2(lo, hi);
    }
}

// ---------------------------------------------------------------------------
// Prep: rope table  tab[n][0..31]=cos, tab[n][32..63]=sin
// ---------------------------------------------------------------------------
__global__ __launch_bounds__(256) void rope_table(float* __restrict__ tab)
{
    int t = blockIdx.x * 256 + threadIdx.x;
    int n = t >> 6, col = t & 63, i = col & 31;
    float ang = (float)n * exp2f(-(float)i * 0.41524101186092029f);
    tab[t] = (col < 32) ? cosf(ang) : sinf(ang);
}

// ---------------------------------------------------------------------------
// bf16 MFMA GEMM: C[M][N] = A[M][K] @ B^T (B = wT[N][K]); global_load_lds
// staging (pre-swizzled source, linear LDS dest). 128x128 tile, BK=64.
// BF16_OUT=1 also applies RoPE to the K region (cols 1024..2047) on fp32 acc.
// ---------------------------------------------------------------------------
template <int BF16_OUT>
__global__ __launch_bounds__(256, 2) void gemm_bf16(
    const u16* __restrict__ A, int lda,
    const u16* __restrict__ B, int ldb,
    void* __restrict__ C, int ldc,
    const float* __restrict__ bias, const float* __restrict__ tab, int K)
{
    __shared__ u16 As[128 * 64];   // 16KB, [row][64k] bf16; chunk cl at cl^(row&7)
    __shared__ u16 Bs[128 * 64];
    const int tid = threadIdx.x;
    const int lane = tid & 63, w = tid >> 6;
    const int g = lane >> 4, c = lane & 15;
    const int wr = w >> 1, wc = w & 1;
    const int rb0 = blockIdx.y * 128, cb0 = blockIdx.x * 128;

    f32x4 acc[4][4];
#pragma unroll
    for (int i = 0; i < 4; ++i)
#pragma unroll
        for (int j = 0; j < 4; ++j) {
            acc[i][j][0] = 0.f; acc[i][j][1] = 0.f; acc[i][j][2] = 0.f; acc[i][j][3] = 0.f;
        }

    const int srow = tid >> 3, sch = tid & 7;
    const int scol = ((sch ^ (srow & 7)) * 8);
    const u16* asrc = A + (size_t)(rb0 + srow) * lda + scol;
    const u16* bsrc = B + (size_t)(cb0 + srow) * ldb + scol;

    for (int k0 = 0; k0 < K; k0 += 64) {
        __syncthreads();
#pragma unroll
        for (int r = 0; r < 4; ++r) {
            gload16(asrc + (size_t)(32 * r) * lda + k0, (char*)As + r * 4096 + w * 1024);
            gload16(bsrc + (size_t)(32 * r) * ldb + k0, (char*)Bs + r * 4096 + w * 1024);
        }
        __syncthreads();
#pragma unroll
        for (int kk = 0; kk < 2; ++kk) {
            s16x8 a[4], b[4];
#pragma unroll
            for (int rb = 0; rb < 4; ++rb) {
                int row = wr * 64 + rb * 16 + c;
                a[rb] = *(const s16x8*)((const char*)As + row * 128 + ((((kk << 2) + g) ^ (row & 7)) << 4));
            }
#pragma unroll
            for (int cb = 0; cb < 4; ++cb) {
                int row = wc * 64 + cb * 16 + c;
                b[cb] = *(const s16x8*)((const char*)Bs + row * 128 + ((((kk << 2) + g) ^ (row & 7)) << 4));
            }
#pragma unroll
            for (int rb = 0; rb < 4; ++rb)
#pragma unroll
                for (int cb = 0; cb < 4; ++cb)
                    acc[rb][cb] = __builtin_amdgcn_mfma_f32_16x16x32_bf16(a[rb], b[cb], acc[rb][cb], 0, 0, 0);
        }
    }

    // ---- fused RoPE on K region (pairs = adjacent cols = adjacent lanes)
    if (BF16_OUT && tab && cb0 >= 1024 && cb0 < 2048) {
#pragma unroll
        for (int rb = 0; rb < 4; ++rb)
#pragma unroll
            for (int cb = 0; cb < 4; ++cb) {
                const int i = ((wc * 64 + cb * 16 + c) & 63) >> 1;
#pragma unroll
                for (int e = 0; e < 4; ++e) {
                    int n = (rb0 + wr * 64 + rb * 16 + g * 4 + e) & (NN - 1);
                    float co = tab[(n << 6) + i], si = tab[(n << 6) + 32 + i];
                    float self = acc[rb][cb][e];
                    float part = __shfl_xor(self, 1);
                    acc[rb][cb][e] = (c & 1) ? fmaf(self, co, part * si)
                                             : fmaf(self, co, -part * si);
                }
            }
    }

#pragma unroll
    for (int rb = 0; rb < 4; ++rb) {
#pragma unroll
        for (int cb = 0; cb < 4; ++cb) {
            if (BF16_OUT) {
                uint2 keep = make_uint2(0, 0);
#pragma unroll
                for (int e = 0; e < 4; ++e) {
                    u32 me = f2bf(acc[rb][cb][e]);
                    u32 x1 = (u32)__shfl_xor((int)me, 1);
                    u32 pair = (c & 1) ? ((x1 & 0xffffu) | (me << 16)) : ((me & 0xffffu) | (x1 << 16));
                    u32 x2 = (u32)__shfl_xor((int)pair, 2);
                    u32 q0 = (c & 2) ? x2 : pair;
                    u32 q1 = (c & 2) ? pair : x2;
                    if ((c & 3) == e) keep = make_uint2(q0, q1);
                }
                int row = rb0 + wr * 64 + rb * 16 + g * 4 + (c & 3);
                int col = cb0 + wc * 64 + cb * 16 + (c & ~3);
                *(uint2*)((u16*)C + (size_t)row * ldc + col) = keep;
            } else {
                int col = cb0 + wc * 64 + cb * 16 + c;
                float bv = bias ? bias[col] : 0.f;
#pragma unroll
                for (int e = 0; e < 4; ++e) {
                    int row = rb0 + wr * 64 + rb * 16 + g * 4 + e;
                    ((float*)C)[(size_t)row * ldc + col] = acc[rb][cb][e] + bv;
                }
            }
        }
    }
}

// ---------------------------------------------------------------------------
// Fused lookahead attention, swapped-layout (lane owns q-row = lane&15).
// Block = (b,h, one 64-row q tile). 1024 blocks, 4 waves x 16 rows, kv tiles
// of 64, dbuf K/V^T. All blocks co-resident (32KB LDS, 64 VGPR -> 4/CU,
// 16 waves/CU). Work imbalance handled statically: qt descending in dispatch
// order; XCD swizzle groups 4 (b,h) panels per XCD for L2. K frag rows
// permuted so softmax'd P lands directly in the PV B-fragment layout
// (zero-shuffle P). Softmax in exp2 domain, rcp-based silu.
// ---------------------------------------------------------------------------
__global__ __launch_bounds__(256, 4) void attn(
    const u16* __restrict__ qkvh, const float* __restrict__ alpha,
    const float* __restrict__ tab, u16* __restrict__ aout)
{
    __shared__ u16 Kb[2][64 * 64];   // 8 KB each
    __shared__ u16 Vt[2][64 * 64];   // 8 KB each

    const int bid = blockIdx.x;
    const int qt = 31 - (bid >> 5);                     // big tiles first
    const int bh = 4 * (bid & 7) + ((bid >> 3) & 3);    // 4 panels per XCD
    const int b = bh >> 4, h = bh & 15;
    const int tid = threadIdx.x;
    const int w = tid >> 6, lane = tid & 63;
    const int g = lane >> 4, c = lane & 15;
    const u16* base = qkvh + (size_t)b * NN * QC;
    const int q0 = qt * 64;
    const int nrow = q0 + w * 16 + c;        // this lane's q row

    // staging indices (srow in [0,32); second call covers srow+32)
    const int srow = tid >> 3, sch = tid & 7;
    const int kscol = (sch ^ ((srow & 3) | (((srow >> 3) & 1) << 2))) * 8;
    const u16* ksrc0 = base + (size_t)srow * QC + 1024 + h * 64 + kscol;
    const u16* vsrc0 = base + (size_t)srow * QC + 2048 + h * 64 + sch * 8;

    const float sig_a = RCP(1.f + EXP2(-alpha[h] * LOG2E));
    const int cbase = (8 * (c >> 2) + (c & 3)) * 128;   // permuted A-row base

    // ---- stage kv tile 0
    gload16(ksrc0, (char*)&Kb[0][0] + w * 1024);
    gload16(ksrc0 + (size_t)32 * QC, (char*)&Kb[0][0] + 4096 + w * 1024);
    uint4 vr0 = *(const uint4*)vsrc0;
    uint4 vr1 = *(const uint4*)(vsrc0 + (size_t)32 * QC);
    vt_write((char*)&Vt[0][0], vr0, srow, sch);
    vt_write((char*)&Vt[0][0], vr1, srow + 32, sch);

    // ---- Q (roped in-register) + HK frags, qhk (log2e-scaled)
    s16x8 qf[2], hf[2];
    float qhL;
    {
        const u16* qp_ = base + (size_t)nrow * QC + h * 64;
        float accq = 0.f;
#pragma unroll
        for (int kk = 0; kk < 2; ++kk) {
            uint4 qv = *(const uint4*)(qp_ + ((kk * 4 + g) * 8));
            uint4 hv = *(const uint4*)(qp_ + 3072 + ((kk * 4 + g) * 8));
            const u16* qe = (const u16*)&qv;
            const u16* he = (const u16*)&hv;
            u32 ow[4];
#pragma unroll
            for (int m2 = 0; m2 < 4; ++m2) {
                int i = (kk * 4 + g) * 4 + m2;
                float co = tab[(nrow << 6) + i], si = tab[(nrow << 6) + 32 + i];
                float x0 = bf2f(qe[2 * m2]), x1 = bf2f(qe[2 * m2 + 1]);
                float r0 = x0 * co - x1 * si;
                float r1 = x1 * co + x0 * si;
                accq += r0 * bf2f(he[2 * m2]) + r1 * bf2f(he[2 * m2 + 1]);
                ow[m2] = (u32)f2bf(r0) | ((u32)f2bf(r1) << 16);
            }
            union { s16x8 v; u32 u[4]; } uq, uh;
            uq.u[0] = ow[0]; uq.u[1] = ow[1]; uq.u[2] = ow[2]; uq.u[3] = ow[3];
            uh.u[0] = hv.x; uh.u[1] = hv.y; uh.u[2] = hv.z; uh.u[3] = hv.w;
            qf[kk] = uq.v; hf[kk] = uh.v;
        }
        accq += __shfl_xor(accq, 16);
        accq += __shfl_xor(accq, 32);
        qhL = accq * SC2;
    }
    __syncthreads();

    // ---- state
    f32x4 y[4];
#pragma unroll
    for (int db = 0; db < 4; ++db) { y[db][0] = 0.f; y[db][1] = 0.f; y[db][2] = 0.f; y[db][3] = 0.f; }
    float m = -INFINITY, l = 0.f;

    for (int kt = 0; kt <= qt; ++kt) {
        const int cur = kt & 1;
        const bool haveNext = (kt < qt);
        uint4 vr0n, vr1n;
        if (haveNext) {
            gload16(ksrc0 + (size_t)((kt + 1) * 64) * QC, (char*)&Kb[cur ^ 1][0] + w * 1024);
            gload16(ksrc0 + (size_t)((kt + 1) * 64 + 32) * QC, (char*)&Kb[cur ^ 1][0] + 4096 + w * 1024);
            vr0n = *(const uint4*)(vsrc0 + (size_t)((kt + 1) * 64) * QC);
            vr1n = *(const uint4*)(vsrc0 + (size_t)((kt + 1) * 64 + 32) * QC);
        }

        // ---- S^T = K.Q^T and HKK^T (swapped, permuted K rows)
        f32x4 sq[4], sh4[4];
#pragma unroll
        for (int kb = 0; kb < 4; ++kb) {
            sq[kb][0] = 0.f; sq[kb][1] = 0.f; sq[kb][2] = 0.f; sq[kb][3] = 0.f;
            sh4[kb][0] = 0.f; sh4[kb][1] = 0.f; sh4[kb][2] = 0.f; sh4[kb][3] = 0.f;
        }
        const char* kbp = (const char*)&Kb[cur][0] + cbase;
#pragma unroll
        for (int kb = 0; kb < 4; ++kb) {
#pragma unroll
            for (int kk = 0; kk < 2; ++kk) {
                s16x8 kf = *(const s16x8*)(kbp + (kb & 1) * 512 + (kb >> 1) * 4096 +
                                           ((((kk << 2) + g) ^ (c & 7)) << 4));
                sq[kb] = __builtin_amdgcn_mfma_f32_16x16x32_bf16(kf, qf[kk], sq[kb], 0, 0, 0);
                sh4[kb] = __builtin_amdgcn_mfma_f32_16x16x32_bf16(kf, hf[kk], sh4[kb], 0, 0, 0);
            }
        }
        // ---- scores (exp2 domain) + mask + online softmax
        const bool needmask = (kt == qt);
        float mx = -INFINITY;
#pragma unroll
        for (int kb = 0; kb < 4; ++kb) {
#pragma unroll
            for (int e = 0; e < 4; ++e) {
                float zp = sh4[kb][e] * qhL;                     // z*log2e
                float sil = zp * RCP(1.f + EXP2(-zp));           // silu(z)*log2e
                float s = fmaf(sq[kb][e], SC2, -sil);            // score*log2e
                if (needmask) {
                    int kg = kt * 64 + 32 * (kb >> 1) + 8 * g + 4 * (kb & 1) + e;
                    if (kg > nrow) s = -INFINITY;
                }
                sq[kb][e] = s;
                mx = fmaxf(mx, s);
            }
        }
        mx = fmaxf(mx, __shfl_xor(mx, 16));
        mx = fmaxf(mx, __shfl_xor(mx, 32));
        const float mnew = fmaxf(m, mx);
        const float scl = EXP2(m - mnew);
        m = mnew;
        float rs = 0.f;
#pragma unroll
        for (int kb = 0; kb < 4; ++kb)
#pragma unroll
            for (int e = 0; e < 4; ++e) {
                float p = EXP2(sq[kb][e] - mnew);
                sq[kb][e] = p;
                rs += p;
            }
        rs += __shfl_xor(rs, 16);
        rs += __shfl_xor(rs, 32);
        l = l * scl + rs;
#pragma unroll
        for (int db = 0; db < 4; ++db) {
            y[db][0] *= scl; y[db][1] *= scl; y[db][2] *= scl; y[db][3] *= scl;
        }
        // ---- pack P into PV B-frag layout (zero-shuffle): j = e + 4*(kb&1)
        union { s16x8 v; u32 u[4]; } pa[2];
#pragma unroll
        for (int kk = 0; kk < 2; ++kk) {
            pa[kk].u[0] = cvtpk(sq[2 * kk][0], sq[2 * kk][1]);
            pa[kk].u[1] = cvtpk(sq[2 * kk][2], sq[2 * kk][3]);
            pa[kk].u[2] = cvtpk(sq[2 * kk + 1][0], sq[2 * kk + 1][1]);
            pa[kk].u[3] = cvtpk(sq[2 * kk + 1][2], sq[2 * kk + 1][3]);
        }
        // ---- y^T += V^T . P^T
        const char* vbp = (const char*)&Vt[cur][0];
#pragma unroll
        for (int kk = 0; kk < 2; ++kk)
#pragma unroll
            for (int db = 0; db < 4; ++db) {
                int row = db * 16 + c;
                int ch = ((kk << 2) + g) ^ (c & 7) ^ (db * 2 + (c >> 3));
                s16x8 vfr = *(const s16x8*)(vbp + row * 128 + (ch << 4));
                y[db] = __builtin_amdgcn_mfma_f32_16x16x32_bf16(vfr, pa[kk].v, y[db], 0, 0, 0);
            }

        if (haveNext) {
            vt_write((char*)&Vt[cur ^ 1][0], vr0n, srow, sch);
            vt_write((char*)&Vt[cur ^ 1][0], vr1n, srow + 32, sch);
        }
        __syncthreads();
    }

    // ---- epilogue: normalize, lookahead correction, store bf16
    const float inv_l = RCP(l);
    const u16* hvp = base + (size_t)nrow * QC + 4096 + h * 64 + g * 4;
    float hv[4][4];
    float sdot = 0.f;
#pragma unroll
    for (int db = 0; db < 4; ++db) {
        uint2 hw = *(const uint2*)(hvp + db * 16);
        const u16* he = (const u16*)&hw;
#pragma unroll
        for (int e = 0; e < 4; ++e) {
            hv[db][e] = bf2f(he[e]);
            float yn = y[db][e] * inv_l;
            y[db][e] = yn;
            sdot += yn * hv[db][e];
        }
    }
    // reduce over dim-groups (lanes differing in g = bits 4,5)
    sdot += __shfl_xor(sdot, 16);
    sdot += __shfl_xor(sdot, 32);
    const float f = sig_a * sdot;
    u16* op = aout + ((size_t)(b * NN + nrow)) * DD + h * 64 + g * 4;
#pragma unroll
    for (int db = 0; db < 4; ++db) {
        u32 o0 = (u32)f2bf(y[db][0] - f * hv[db][0]) | ((u32)f2bf(y[db][1] - f * hv[db][1]) << 16);
        u32 o1 = (u32)f2bf(y[db][2] - f * hv[db][2]) | ((u32)f2bf(y[db][3] - f * hv[db][3]) << 16);
        *(uint2*)(op + db * 16) = make_uint2(o0, o1);
    }
}

// ---------------------------------------------------------------------------
extern "C" void kernel_launch(void* const* d_in, const int* in_sizes, int n_in,
                              void* d_out, int out_size, void* d_ws, size_t ws_size,
                              hipStream_t stream)
{
    const float* x     = (const float*)d_in[0];
    const float* w_qkv = (const float*)d_in[1];
    const float* w_hkv = (const float*)d_in[2];
    const float* w_out = (const float*)d_in[3];
    const float* b_out = (const float*)d_in[4];
    const float* alpha = (const float*)d_in[5];

    char* ws = (char*)d_ws;
    u16*   qkvh = (u16*)ws;                       // 4096x5120 bf16
    uint4* xb   = (uint4*)(ws + 41943040);        // 4096x1024 bf16
    u16*   wT   = (u16*)(ws + 50331648);          // 6144x1024 bf16
    u16*   aout = (u16*)(ws + 62914560);          // 4096x1024 bf16
    float* tab  = (float*)(ws + 71303168);        // 2048x64 f32

    convert_x<<<2048, 256, 0, stream>>>(x, xb);
    transpose_w<<<dim3(96, 16), 256, 0, stream>>>(w_qkv, w_hkv, w_out, wT);
    rope_table<<<512, 256, 0, stream>>>(tab);

    // 1) qkvh = x @ [w_qkv | w_hkv]  (+ fused K-RoPE in epilogue)
    gemm_bf16<1><<<dim3(40, 32), 256, 0, stream>>>(
        (const u16*)xb, 1024, wT, 1024, qkvh, QC, nullptr, tab, 1024);

    // 2) fused attention -> aout  (Q roped in-register inside)
    attn<<<1024, 256, 0, stream>>>(qkvh, alpha, tab, aout);

    // 3) out = aout @ w_out + b_out
    gemm_bf16<0><<<dim3(8, 32), 256, 0, stream>>>(
        aout, 1024, wT + 5120 * 1024, 1024, d_out, 1024, b_out, nullptr, 1024);
}

// Round 7
// 165.816 us; speedup vs baseline: 20.4154x; 1.0160x over previous
//
#include <hip/hip_runtime.h>
#include <math.h>

typedef unsigned int u32;
typedef unsigned short u16;
typedef __attribute__((ext_vector_type(4))) float f32x4;
typedef __attribute__((ext_vector_type(8))) short s16x8;   // 8 bf16 (MFMA A/B frag)

#define BB 2
#define NN 2048
#define DD 1024
#define HH 16
#define ROWS 4096
#define QC 5120            // qkvh cols: q|k|v|hk|hv
#define SCALE 0.125f
#define LOG2E 1.44269504088896f
#define SC2 (SCALE * LOG2E)
#define DEFER_THR 8.0f

#if __has_builtin(__builtin_amdgcn_exp2f)
#define EXP2(x) __builtin_amdgcn_exp2f(x)
#else
#define EXP2(x) __expf((x) * 0.69314718056f)
#endif
#if __has_builtin(__builtin_amdgcn_rcpf)
#define RCP(x) __builtin_amdgcn_rcpf(x)
#else
#define RCP(x) (1.0f / (x))
#endif

__device__ __forceinline__ u16 f2bf(float x) {
    u32 u = __float_as_uint(x);
    return (u16)((u + 0x7FFFu + ((u >> 16) & 1u)) >> 16);
}
__device__ __forceinline__ float bf2f(u16 h) {
    return __uint_as_float(((u32)h) << 16);
}
__device__ __forceinline__ u32 cvtpk(float lo, float hi) {
    u32 r;
    asm("v_cvt_pk_bf16_f32 %0, %1, %2" : "=v"(r) : "v"(lo), "v"(hi));
    return r;
}
__device__ __forceinline__ void gload16(const void* g, void* l) {
    __builtin_amdgcn_global_load_lds(
        (const __attribute__((address_space(1))) unsigned int*)g,
        (__attribute__((address_space(3))) unsigned int*)l, 16, 0, 0);
}

// Transpose a 64x64 V tile into Vt[d][kv] (bf16-pair packed, XOR-swizzled
// chunks). Thread holds V[srow][sch*8..+7] in vreg; partner (srow^1 = tid^8,
// same sch) supplies the adjacent kv row. Even srow writes dims sch*8..+3,
// odd writes sch*8+4..+7, for kv pair (2s,2s+1), s = srow>>1. Slot:
// d*128 + ((s>>2)^(d&7)^(d>>3))*16 + (s&3)*4  — bijective; the ^(d>>3)
// (= sch) term spreads a wave's stores across all 32 banks (2 lanes/bank).
__device__ __forceinline__ void vt_write(char* vbb, uint4 vreg, int srow, int sch)
{
    uint4 oth;
    oth.x = (u32)__shfl_xor((int)vreg.x, 8); oth.y = (u32)__shfl_xor((int)vreg.y, 8);
    oth.z = (u32)__shfl_xor((int)vreg.z, 8); oth.w = (u32)__shfl_xor((int)vreg.w, 8);
    const bool odd = (srow & 1);
    u32 ma = odd ? vreg.z : vreg.x, mb = odd ? vreg.w : vreg.y;
    u32 oa = odd ? oth.z : oth.x,  ob = odd ? oth.w : oth.y;
    u32 ea = odd ? oa : ma, eb = odd ? ob : mb;   // even kv row (2s)
    u32 da = odd ? ma : oa, db = odd ? mb : ob;   // odd  kv row (2s+1)
    u32 pk0 = (ea & 0xffffu) | (da << 16);
    u32 pk1 = (ea >> 16)     | (da & 0xffff0000u);
    u32 pk2 = (eb & 0xffffu) | (db << 16);
    u32 pk3 = (eb >> 16)     | (db & 0xffff0000u);
    const int s = srow >> 1;
    const int d0 = sch * 8 + (odd ? 4 : 0);
    const int sb = (s & 3) * 4;
    *(u32*)(vbb + (d0 + 0) * 128 + ((((s >> 2) ^ ((d0 + 0) & 7) ^ sch) << 4)) + sb) = pk0;
    *(u32*)(vbb + (d0 + 1) * 128 + ((((s >> 2) ^ ((d0 + 1) & 7) ^ sch) << 4)) + sb) = pk1;
    *(u32*)(vbb + (d0 + 2) * 128 + ((((s >> 2) ^ ((d0 + 2) & 7) ^ sch) << 4)) + sb) = pk2;
    *(u32*)(vbb + (d0 + 3) * 128 + ((((s >> 2) ^ ((d0 + 3) & 7) ^ sch) << 4)) + sb) = pk3;
}

// ---------------------------------------------------------------------------
// Prep: x (f32) -> bf16
// ---------------------------------------------------------------------------
__global__ __launch_bounds__(256) void convert_x(const float* __restrict__ x,
                                                 uint4* __restrict__ xb)
{
    int t = blockIdx.x * 256 + threadIdx.x;
    const float4 a = ((const float4*)x)[2 * t];
    const float4 b = ((const float4*)x)[2 * t + 1];
    uint4 o;
    o.x = f2bf(a.x) | ((u32)f2bf(a.y) << 16);
    o.y = f2bf(a.z) | ((u32)f2bf(a.w) << 16);
    o.z = f2bf(b.x) | ((u32)f2bf(b.y) << 16);
    o.w = f2bf(b.z) | ((u32)f2bf(b.w) << 16);
    xb[t] = o;
}

// ---------------------------------------------------------------------------
// Prep: weights -> wT[c][k] bf16 (rows 0..5119 = [wqkv|whkv], 5120.. = w_out^T)
// ---------------------------------------------------------------------------
__global__ __launch_bounds__(256) void transpose_w(const float* __restrict__ wqkv,
                                                   const float* __restrict__ whkv,
                                                   const float* __restrict__ wout,
                                                   u16* __restrict__ wT)
{
    __shared__ float T[64][65];
    const int bc = blockIdx.x;
    const int k0 = blockIdx.y * 64;
    const int c0 = bc * 64;
    const float* src; int stride; int csrc;
    if (bc < 48)      { src = wqkv; stride = 3072; csrc = c0; }
    else if (bc < 80) { src = whkv; stride = 2048; csrc = c0 - 3072; }
    else              { src = wout; stride = 1024; csrc = c0 - 5120; }
    const int t = threadIdx.x;
    const int r = t >> 4, c4 = t & 15;
#pragma unroll
    for (int i = 0; i < 4; ++i) {
        int kk = r + 16 * i;
        float4 v = *(const float4*)&src[(size_t)(k0 + kk) * stride + csrc + 4 * c4];
        T[kk][4 * c4 + 0] = v.x; T[kk][4 * c4 + 1] = v.y;
        T[kk][4 * c4 + 2] = v.z; T[kk][4 * c4 + 3] = v.w;
    }
    __syncthreads();
#pragma unroll
    for (int i = 0; i < 4; ++i) {
        int cc = r + 16 * i;
        u32 lo = f2bf(T[4 * c4 + 0][cc]) | ((u32)f2bf(T[4 * c4 + 1][cc]) << 16);
        u32 hi = f2bf(T[4 * c4 + 2][cc]) | ((u32)f2bf(T[4 * c4 + 3][cc]) << 16);
        *(uint2*)&wT[(size_t)(c0 + cc) * 1024 + k0 + 4 * c4] = make_uint2(lo, hi);
    }
}

// ---------------------------------------------------------------------------
// Prep: rope table  tab[n][0..31]=cos, tab[n][32..63]=sin
// ---------------------------------------------------------------------------
__global__ __launch_bounds__(256) void rope_table(float* __restrict__ tab)
{
    int t = blockIdx.x * 256 + threadIdx.x;
    int n = t >> 6, col = t & 63, i = col & 31;
    float ang = (float)n * exp2f(-(float)i * 0.41524101186092029f);
    tab[t] = (col < 32) ? cosf(ang) : sinf(ang);
}

// ---------------------------------------------------------------------------
// bf16 MFMA GEMM: C[M][N] = A[M][K] @ B^T (B = wT[N][K]); global_load_lds
// staging (pre-swizzled source, linear LDS dest). 128x128 tile, BK=64.
// T3-minimum double-buffer: stage next K-tile before computing current,
// one barrier per K-step (loads in flight under the MFMA cluster).
// BF16_OUT=1 also applies RoPE to the K region (cols 1024..2047) on fp32 acc.
// ---------------------------------------------------------------------------
template <int BF16_OUT>
__global__ __launch_bounds__(256, 2) void gemm_bf16(
    const u16* __restrict__ A, int lda,
    const u16* __restrict__ B, int ldb,
    void* __restrict__ C, int ldc,
    const float* __restrict__ bias, const float* __restrict__ tab, int K)
{
    __shared__ u16 As[2][128 * 64];   // 2 x 16KB
    __shared__ u16 Bs[2][128 * 64];
    const int tid = threadIdx.x;
    const int lane = tid & 63, w = tid >> 6;
    const int g = lane >> 4, c = lane & 15;
    const int wr = w >> 1, wc = w & 1;
    const int rb0 = blockIdx.y * 128, cb0 = blockIdx.x * 128;

    f32x4 acc[4][4];
#pragma unroll
    for (int i = 0; i < 4; ++i)
#pragma unroll
        for (int j = 0; j < 4; ++j) {
            acc[i][j][0] = 0.f; acc[i][j][1] = 0.f; acc[i][j][2] = 0.f; acc[i][j][3] = 0.f;
        }

    const int srow = tid >> 3, sch = tid & 7;
    const int scol = ((sch ^ (srow & 7)) * 8);
    const u16* asrc = A + (size_t)(rb0 + srow) * lda + scol;
    const u16* bsrc = B + (size_t)(cb0 + srow) * ldb + scol;

    // prologue: stage K-step 0 into buf 0
#pragma unroll
    for (int r = 0; r < 4; ++r) {
        gload16(asrc + (size_t)(32 * r) * lda, (char*)As[0] + r * 4096 + w * 1024);
        gload16(bsrc + (size_t)(32 * r) * ldb, (char*)Bs[0] + r * 4096 + w * 1024);
    }
    __syncthreads();

    const int NKS = K >> 6;
    for (int ks = 0; ks < NKS; ++ks) {
        const int cur = ks & 1;
        if (ks + 1 < NKS) {   // stage next K-step into the other buffer
            const int k1 = (ks + 1) << 6;
#pragma unroll
            for (int r = 0; r < 4; ++r) {
                gload16(asrc + (size_t)(32 * r) * lda + k1, (char*)As[cur ^ 1] + r * 4096 + w * 1024);
                gload16(bsrc + (size_t)(32 * r) * ldb + k1, (char*)Bs[cur ^ 1] + r * 4096 + w * 1024);
            }
        }
#pragma unroll
        for (int kk = 0; kk < 2; ++kk) {
            s16x8 a[4], b[4];
#pragma unroll
            for (int rb = 0; rb < 4; ++rb) {
                int row = wr * 64 + rb * 16 + c;
                a[rb] = *(const s16x8*)((const char*)As[cur] + row * 128 + ((((kk << 2) + g) ^ (row & 7)) << 4));
            }
#pragma unroll
            for (int cb = 0; cb < 4; ++cb) {
                int row = wc * 64 + cb * 16 + c;
                b[cb] = *(const s16x8*)((const char*)Bs[cur] + row * 128 + ((((kk << 2) + g) ^ (row & 7)) << 4));
            }
            __builtin_amdgcn_s_setprio(1);
#pragma unroll
            for (int rb = 0; rb < 4; ++rb)
#pragma unroll
                for (int cb = 0; cb < 4; ++cb)
                    acc[rb][cb] = __builtin_amdgcn_mfma_f32_16x16x32_bf16(a[rb], b[cb], acc[rb][cb], 0, 0, 0);
            __builtin_amdgcn_s_setprio(0);
        }
        __syncthreads();   // implicit vmcnt(0): next-buf staging landed; cur free
    }

    // ---- fused RoPE on K region (pairs = adjacent cols = adjacent lanes)
    if (BF16_OUT && tab && cb0 >= 1024 && cb0 < 2048) {
#pragma unroll
        for (int rb = 0; rb < 4; ++rb)
#pragma unroll
            for (int cb = 0; cb < 4; ++cb) {
                const int i = ((wc * 64 + cb * 16 + c) & 63) >> 1;
#pragma unroll
                for (int e = 0; e < 4; ++e) {
                    int n = (rb0 + wr * 64 + rb * 16 + g * 4 + e) & (NN - 1);
                    float co = tab[(n << 6) + i], si = tab[(n << 6) + 32 + i];
                    float self = acc[rb][cb][e];
                    float part = __shfl_xor(self, 1);
                    acc[rb][cb][e] = (c & 1) ? fmaf(self, co, part * si)
                                             : fmaf(self, co, -part * si);
                }
            }
    }

#pragma unroll
    for (int rb = 0; rb < 4; ++rb) {
#pragma unroll
        for (int cb = 0; cb < 4; ++cb) {
            if (BF16_OUT) {
                uint2 keep = make_uint2(0, 0);
#pragma unroll
                for (int e = 0; e < 4; ++e) {
                    u32 me = f2bf(acc[rb][cb][e]);
                    u32 x1 = (u32)__shfl_xor((int)me, 1);
                    u32 pair = (c & 1) ? ((x1 & 0xffffu) | (me << 16)) : ((me & 0xffffu) | (x1 << 16));
                    u32 x2 = (u32)__shfl_xor((int)pair, 2);
                    u32 q0 = (c & 2) ? x2 : pair;
                    u32 q1 = (c & 2) ? pair : x2;
                    if ((c & 3) == e) keep = make_uint2(q0, q1);
                }
                int row = rb0 + wr * 64 + rb * 16 + g * 4 + (c & 3);
                int col = cb0 + wc * 64 + cb * 16 + (c & ~3);
                *(uint2*)((u16*)C + (size_t)row * ldc + col) = keep;
            } else {
                int col = cb0 + wc * 64 + cb * 16 + c;
                float bv = bias ? bias[col] : 0.f;
#pragma unroll
                for (int e = 0; e < 4; ++e) {
                    int row = rb0 + wr * 64 + rb * 16 + g * 4 + e;
                    ((float*)C)[(size_t)row * ldc + col] = acc[rb][cb][e] + bv;
                }
            }
        }
    }
}

// ---------------------------------------------------------------------------
// Fused lookahead attention, swapped-layout (lane owns q-row = lane&15).
// Block = (b,h, one 64-row q tile). 1024 blocks, 4 waves x 16 rows, kv tiles
// of 64, dbuf K/V^T. Defer-max (THR=8, exp2 domain) skips y/l rescale when
// the running max doesn't grow materially. setprio(1) around MFMA clusters.
// K frag rows permuted so softmax'd P lands directly in the PV B-fragment
// layout (zero-shuffle P). Softmax in exp2 domain, rcp-based silu.
// ---------------------------------------------------------------------------
__global__ __launch_bounds__(256, 4) void attn(
    const u16* __restrict__ qkvh, const float* __restrict__ alpha,
    const float* __restrict__ tab, u16* __restrict__ aout)
{
    __shared__ u16 Kb[2][64 * 64];   // 8 KB each
    __shared__ u16 Vt[2][64 * 64];   // 8 KB each

    const int bid = blockIdx.x;
    const int qt = 31 - (bid >> 5);                     // big tiles first
    const int bh = 4 * (bid & 7) + ((bid >> 3) & 3);    // 4 panels per XCD
    const int b = bh >> 4, h = bh & 15;
    const int tid = threadIdx.x;
    const int w = tid >> 6, lane = tid & 63;
    const int g = lane >> 4, c = lane & 15;
    const u16* base = qkvh + (size_t)b * NN * QC;
    const int q0 = qt * 64;
    const int nrow = q0 + w * 16 + c;        // this lane's q row

    // staging indices (srow in [0,32); second call covers srow+32)
    const int srow = tid >> 3, sch = tid & 7;
    const int kscol = (sch ^ ((srow & 3) | (((srow >> 3) & 1) << 2))) * 8;
    const u16* ksrc0 = base + (size_t)srow * QC + 1024 + h * 64 + kscol;
    const u16* vsrc0 = base + (size_t)srow * QC + 2048 + h * 64 + sch * 8;

    const float sig_a = RCP(1.f + EXP2(-alpha[h] * LOG2E));
    const int cbase = (8 * (c >> 2) + (c & 3)) * 128;   // permuted A-row base

    // ---- stage kv tile 0
    gload16(ksrc0, (char*)&Kb[0][0] + w * 1024);
    gload16(ksrc0 + (size_t)32 * QC, (char*)&Kb[0][0] + 4096 + w * 1024);
    uint4 vr0 = *(const uint4*)vsrc0;
    uint4 vr1 = *(const uint4*)(vsrc0 + (size_t)32 * QC);
    vt_write((char*)&Vt[0][0], vr0, srow, sch);
    vt_write((char*)&Vt[0][0], vr1, srow + 32, sch);

    // ---- Q (roped in-register) + HK frags, qhk (log2e-scaled)
    s16x8 qf[2], hf[2];
    float qhL;
    {
        const u16* qp_ = base + (size_t)nrow * QC + h * 64;
        float accq = 0.f;
#pragma unroll
        for (int kk = 0; kk < 2; ++kk) {
            uint4 qv = *(const uint4*)(qp_ + ((kk * 4 + g) * 8));
            uint4 hv = *(const uint4*)(qp_ + 3072 + ((kk * 4 + g) * 8));
            const u16* qe = (const u16*)&qv;
            const u16* he = (const u16*)&hv;
            u32 ow[4];
#pragma unroll
            for (int m2 = 0; m2 < 4; ++m2) {
                int i = (kk * 4 + g) * 4 + m2;
                float co = tab[(nrow << 6) + i], si = tab[(nrow << 6) + 32 + i];
                float x0 = bf2f(qe[2 * m2]), x1 = bf2f(qe[2 * m2 + 1]);
                float r0 = x0 * co - x1 * si;
                float r1 = x1 * co + x0 * si;
                accq += r0 * bf2f(he[2 * m2]) + r1 * bf2f(he[2 * m2 + 1]);
                ow[m2] = (u32)f2bf(r0) | ((u32)f2bf(r1) << 16);
            }
            union { s16x8 v; u32 u[4]; } uq, uh;
            uq.u[0] = ow[0]; uq.u[1] = ow[1]; uq.u[2] = ow[2]; uq.u[3] = ow[3];
            uh.u[0] = hv.x; uh.u[1] = hv.y; uh.u[2] = hv.z; uh.u[3] = hv.w;
            qf[kk] = uq.v; hf[kk] = uh.v;
        }
        accq += __shfl_xor(accq, 16);
        accq += __shfl_xor(accq, 32);
        qhL = accq * SC2;
    }
    __syncthreads();

    // ---- state
    f32x4 y[4];
#pragma unroll
    for (int db = 0; db < 4; ++db) { y[db][0] = 0.f; y[db][1] = 0.f; y[db][2] = 0.f; y[db][3] = 0.f; }
    float m = -INFINITY, l = 0.f;

    for (int kt = 0; kt <= qt; ++kt) {
        const int cur = kt & 1;
        const bool haveNext = (kt < qt);
        uint4 vr0n, vr1n;
        if (haveNext) {
            gload16(ksrc0 + (size_t)((kt + 1) * 64) * QC, (char*)&Kb[cur ^ 1][0] + w * 1024);
            gload16(ksrc0 + (size_t)((kt + 1) * 64 + 32) * QC, (char*)&Kb[cur ^ 1][0] + 4096 + w * 1024);
            vr0n = *(const uint4*)(vsrc0 + (size_t)((kt + 1) * 64) * QC);
            vr1n = *(const uint4*)(vsrc0 + (size_t)((kt + 1) * 64 + 32) * QC);
        }

        // ---- S^T = K.Q^T and HKK^T (swapped, permuted K rows)
        f32x4 sq[4], sh4[4];
#pragma unroll
        for (int kb = 0; kb < 4; ++kb) {
            sq[kb][0] = 0.f; sq[kb][1] = 0.f; sq[kb][2] = 0.f; sq[kb][3] = 0.f;
            sh4[kb][0] = 0.f; sh4[kb][1] = 0.f; sh4[kb][2] = 0.f; sh4[kb][3] = 0.f;
        }
        const char* kbp = (const char*)&Kb[cur][0] + cbase;
        __builtin_amdgcn_s_setprio(1);
#pragma unroll
        for (int kb = 0; kb < 4; ++kb) {
#pragma unroll
            for (int kk = 0; kk < 2; ++kk) {
                s16x8 kf = *(const s16x8*)(kbp + (kb & 1) * 512 + (kb >> 1) * 4096 +
                                           ((((kk << 2) + g) ^ (c & 7)) << 4));
                sq[kb] = __builtin_amdgcn_mfma_f32_16x16x32_bf16(kf, qf[kk], sq[kb], 0, 0, 0);
                sh4[kb] = __builtin_amdgcn_mfma_f32_16x16x32_bf16(kf, hf[kk], sh4[kb], 0, 0, 0);
            }
        }
        __builtin_amdgcn_s_setprio(0);
        // ---- scores (exp2 domain) + mask + online softmax
        const bool needmask = (kt == qt);
        float mx = -INFINITY;
#pragma unroll
        for (int kb = 0; kb < 4; ++kb) {
#pragma unroll
            for (int e = 0; e < 4; ++e) {
                float zp = sh4[kb][e] * qhL;                     // z*log2e
                float sil = zp * RCP(1.f + EXP2(-zp));           // silu(z)*log2e
                float s = fmaf(sq[kb][e], SC2, -sil);            // score*log2e
                if (needmask) {
                    int kg = kt * 64 + 32 * (kb >> 1) + 8 * g + 4 * (kb & 1) + e;
                    if (kg > nrow) s = -INFINITY;
                }
                sq[kb][e] = s;
                mx = fmaxf(mx, s);
            }
        }
        mx = fmaxf(mx, __shfl_xor(mx, 16));
        mx = fmaxf(mx, __shfl_xor(mx, 32));
        // defer-max: only rebase when the max grows materially (p <= 2^THR)
        if (!__all(mx <= m + DEFER_THR)) {
            const float mnew = fmaxf(m, mx);
            const float scl = EXP2(m - mnew);
            m = mnew;
            l *= scl;
#pragma unroll
            for (int db = 0; db < 4; ++db) {
                y[db][0] *= scl; y[db][1] *= scl; y[db][2] *= scl; y[db][3] *= scl;
            }
        }
        float rs = 0.f;
#pragma unroll
        for (int kb = 0; kb < 4; ++kb)
#pragma unroll
            for (int e = 0; e < 4; ++e) {
                float p = EXP2(sq[kb][e] - m);
                sq[kb][e] = p;
                rs += p;
            }
        rs += __shfl_xor(rs, 16);
        rs += __shfl_xor(rs, 32);
        l += rs;
        // ---- pack P into PV B-frag layout (zero-shuffle): j = e + 4*(kb&1)
        union { s16x8 v; u32 u[4]; } pa[2];
#pragma unroll
        for (int kk = 0; kk < 2; ++kk) {
            pa[kk].u[0] = cvtpk(sq[2 * kk][0], sq[2 * kk][1]);
            pa[kk].u[1] = cvtpk(sq[2 * kk][2], sq[2 * kk][3]);
            pa[kk].u[2] = cvtpk(sq[2 * kk + 1][0], sq[2 * kk + 1][1]);
            pa[kk].u[3] = cvtpk(sq[2 * kk + 1][2], sq[2 * kk + 1][3]);
        }
        // ---- y^T += V^T . P^T
        const char* vbp = (const char*)&Vt[cur][0];
        __builtin_amdgcn_s_setprio(1);
#pragma unroll
        for (int kk = 0; kk < 2; ++kk)
#pragma unroll
            for (int db = 0; db < 4; ++db) {
                int row = db * 16 + c;
                int ch = ((kk << 2) + g) ^ (c & 7) ^ (db * 2 + (c >> 3));
                s16x8 vfr = *(const s16x8*)(vbp + row * 128 + (ch << 4));
                y[db] = __builtin_amdgcn_mfma_f32_16x16x32_bf16(vfr, pa[kk].v, y[db], 0, 0, 0);
            }
        __builtin_amdgcn_s_setprio(0);

        if (haveNext) {
            vt_write((char*)&Vt[cur ^ 1][0], vr0n, srow, sch);
            vt_write((char*)&Vt[cur ^ 1][0], vr1n, srow + 32, sch);
        }
        __syncthreads();
    }

    // ---- epilogue: normalize, lookahead correction, store bf16
    const float inv_l = RCP(l);
    const u16* hvp = base + (size_t)nrow * QC + 4096 + h * 64 + g * 4;
    float hv[4][4];
    float sdot = 0.f;
#pragma unroll
    for (int db = 0; db < 4; ++db) {
        uint2 hw = *(const uint2*)(hvp + db * 16);
        const u16* he = (const u16*)&hw;
#pragma unroll
        for (int e = 0; e < 4; ++e) {
            hv[db][e] = bf2f(he[e]);
            float yn = y[db][e] * inv_l;
            y[db][e] = yn;
            sdot += yn * hv[db][e];
        }
    }
    // reduce over dim-groups (lanes differing in g = bits 4,5)
    sdot += __shfl_xor(sdot, 16);
    sdot += __shfl_xor(sdot, 32);
    const float f = sig_a * sdot;
    u16* op = aout + ((size_t)(b * NN + nrow)) * DD + h * 64 + g * 4;
#pragma unroll
    for (int db = 0; db < 4; ++db) {
        u32 o0 = (u32)f2bf(y[db][0] - f * hv[db][0]) | ((u32)f2bf(y[db][1] - f * hv[db][1]) << 16);
        u32 o1 = (u32)f2bf(y[db][2] - f * hv[db][2]) | ((u32)f2bf(y[db][3] - f * hv[db][3]) << 16);
        *(uint2*)(op + db * 16) = make_uint2(o0, o1);
    }
}

// ---------------------------------------------------------------------------
extern "C" void kernel_launch(void* const* d_in, const int* in_sizes, int n_in,
                              void* d_out, int out_size, void* d_ws, size_t ws_size,
                              hipStream_t stream)
{
    const float* x     = (const float*)d_in[0];
    const float* w_qkv = (const float*)d_in[1];
    const float* w_hkv = (const float*)d_in[2];
    const float* w_out = (const float*)d_in[3];
    const float* b_out = (const float*)d_in[4];
    const float* alpha = (const float*)d_in[5];

    char* ws = (char*)d_ws;
    u16*   qkvh = (u16*)ws;                       // 4096x5120 bf16
    uint4* xb   = (uint4*)(ws + 41943040);        // 4096x1024 bf16
    u16*   wT   = (u16*)(ws + 50331648);          // 6144x1024 bf16
    u16*   aout = (u16*)(ws + 62914560);          // 4096x1024 bf16
    float* tab  = (float*)(ws + 71303168);        // 2048x64 f32

    convert_x<<<2048, 256, 0, stream>>>(x, xb);
    transpose_w<<<dim3(96, 16), 256, 0, stream>>>(w_qkv, w_hkv, w_out, wT);
    rope_table<<<512, 256, 0, stream>>>(tab);

    // 1) qkvh = x @ [w_qkv | w_hkv]  (+ fused K-RoPE in epilogue)
    gemm_bf16<1><<<dim3(40, 32), 256, 0, stream>>>(
        (const u16*)xb, 1024, wT, 1024, qkvh, QC, nullptr, tab, 1024);

    // 2) fused attention -> aout  (Q roped in-register inside)
    attn<<<1024, 256, 0, stream>>>(qkvh, alpha, tab, aout);

    // 3) out = aout @ w_out + b_out
    gemm_bf16<0><<<dim3(8, 32), 256, 0, stream>>>(
        aout, 1024, wT + 5120 * 1024, 1024, d_out, 1024, b_out, nullptr, 1024);
}